// Round 6
// baseline (886.525 us; speedup 1.0000x reference)
//
#include <hip/hip_runtime.h>

// EGA multi-headed attention, MI355X/gfx950.
// Round 6: all GEMMs -> global_load_lds(16B) copy-only staging, double-buffered
//          2-phase loop, linear LDS tiles. query/key/value pre-split once into
//          f16 hi/lo planes (time-shared 64MB region). Same numerics as r5.
// Dims fixed: B=8, L=S=2048, E=1024, H=16, G=64, Ek=Ev=64, KD=VD=1024.

typedef float f32x4 __attribute__((ext_vector_type(4)));
typedef _Float16 f16x8 __attribute__((ext_vector_type(8)));
typedef unsigned short u16;

#define DEV static __device__ __forceinline__

DEV u16 f2h(float x){
  _Float16 h = (_Float16)x;
  return __builtin_bit_cast(u16, h);
}
DEV float h2f(u16 u){
  return (float)__builtin_bit_cast(_Float16, u);
}
DEV void split1h(float x, u16 &h, u16 &l){
  h = f2h(x);
  l = f2h(x - h2f(h));
}
DEV void split2pkh(float a, float b, unsigned &h, unsigned &l){
  u16 ha, la, hb, lb;
  split1h(a, ha, la); split1h(b, hb, lb);
  h = (unsigned)ha | ((unsigned)hb << 16);
  l = (unsigned)la | ((unsigned)lb << 16);
}

// async global->LDS, 16B per lane; dst is wave-uniform base (HW adds lane*16)
DEV void gload16(const u16* src, u16* dst_lds){
  __builtin_amdgcn_global_load_lds(
      (__attribute__((address_space(1))) void*)src,
      (__attribute__((address_space(3))) void*)dst_lds, 16, 0, 0);
}

// ---------------- mask dtype sniff + normalize to uchar ----------------
__global__ __launch_bounds__(256)
void mask_norm(const unsigned char* __restrict__ src, unsigned char* __restrict__ dst, int n)
{
  const unsigned* w = (const unsigned*)src;
  const int tid = threadIdx.x;
  int local = 0;
  for (int i = tid; i < n/4; i += 256){
    unsigned v = w[i];
    if (v == 0x3F800000u) local |= 2;
    else if (v > 1u)      local |= 1;
  }
  __shared__ int red[256];
  red[tid] = local;
  __syncthreads();
  for (int s = 128; s; s >>= 1){
    if (tid < s) red[tid] |= red[tid+s];
    __syncthreads();
  }
  const int r = red[0];
  const int mode = (r & 2) ? 2 : ((r & 1) ? 1 : 0);   // 2=f32, 1=u8, 0=i32
  for (int i = tid; i < n; i += 256){
    unsigned char v;
    if (mode == 1) v = src[i] ? 1 : 0;
    else           v = w[i]   ? 1 : 0;
    dst[i] = v;
  }
}

// ---------------- fp32 -> f16 hi/lo planes (flat, 8 elems/thread) ----------------
__global__ __launch_bounds__(256)
void conv_split(const float* __restrict__ x, u16* __restrict__ hi, u16* __restrict__ lo, int n8)
{
  const int i = blockIdx.x*256 + threadIdx.x;
  if (i >= n8) return;
  f32x4 a = ((const f32x4*)x)[2*i], b = ((const f32x4*)x)[2*i+1];
  uint4 uh, ul;
  split2pkh(a[0], a[1], uh.x, ul.x);
  split2pkh(a[2], a[3], uh.y, ul.y);
  split2pkh(b[0], b[1], uh.z, ul.z);
  split2pkh(b[2], b[3], uh.w, ul.w);
  ((uint4*)hi)[i] = uh;
  ((uint4*)lo)[i] = ul;
}

// ---------------- 1024x1024 transpose, fp32 -> split f16 planes (lo optional) ----------------
__global__ __launch_bounds__(256)
void transpose_split(const float* __restrict__ Wsrc,
                     u16* __restrict__ Whi, u16* __restrict__ Wlo,
                     int Kd, int Nd)
{
  __shared__ float t[64][65];
  const int tid = threadIdx.x;
  const int n0 = blockIdx.x * 64, k0 = blockIdx.y * 64;
  #pragma unroll
  for (int it = 0; it < 16; ++it){
    int e = it*256 + tid, r = e >> 6, c = e & 63;
    t[r][c] = Wsrc[(long)(k0+r)*Nd + (n0+c)];
  }
  __syncthreads();
  #pragma unroll
  for (int it = 0; it < 16; ++it){
    int e = it*256 + tid, r = e >> 6, c = e & 63;
    u16 h, l;
    split1h(t[c][r], h, l);
    const long idx = (long)(n0+r)*Kd + (k0+c);
    Whi[idx] = h;
    if (Wlo) Wlo[idx] = l;
  }
}

// ---------------- f16 2-term MFMA GEMM, global_load_lds staging, dbuf ----------------
// C[m,n] = sum_k A[m,k]*Bt[n,k].  A = hi+lo planes, B = hi plane (copy-only).
// CM: 0 = fp32 out; 1 = split f16 planes out.  EPI==1: scale+mask epilogue.
template<int TM, int CM, int EPI>
__global__ __launch_bounds__(256)
void gemm_g(const u16* __restrict__ Ah_g, const u16* __restrict__ Al_g,
            const u16* __restrict__ Bh_g,
            void* __restrict__ Cp, void* __restrict__ Cp2,
            const unsigned char* __restrict__ maskp,
            int K, int lda, int ldb, int ldc,
            long aB, long aH, long bB, long bH, long cB, long cH,
            int H2, int Ssz, float scale)
{
  constexpr int BN = 128, BK = 32;
  constexpr int WM = TM/2, WN = BN/2;
  constexpr int FM = WM/16, FN = WN/16;
  // linear tiles (row = 32 u16 = 64B), double buffered
  __shared__ __align__(16) u16 AhS[2][TM*BK];
  __shared__ __align__(16) u16 AlS[2][TM*BK];
  __shared__ __align__(16) u16 BhS[2][BN*BK];

  const int tid = threadIdx.x;
  const int batch = blockIdx.z;
  const int b = batch / H2, h = batch - b*H2;
  const long aOff = (long)b*aB + (long)h*aH;
  const long bOff = (long)b*bB + (long)h*bH;
  const long cOff = (long)b*cB + (long)h*cH;
  const int nBase = blockIdx.x * BN;
  const int mBase = blockIdx.y * TM;
  const int wave = tid >> 6, lane = tid & 63;
  const int wm = wave >> 1, wn = wave & 1;
  const int cg8 = (lane & 3) * 8;       // 16B column group within a 64B row
  const int rsub = lane >> 2;           // row within a 16-row chunk

  auto stage = [&](int buf, int k0){
    #pragma unroll
    for (int c = 0; c < TM/64; ++c){
      const int chunk = wave*(TM/64) + c;
      const long g = aOff + (long)(mBase + chunk*16 + rsub)*lda + k0 + cg8;
      gload16(Ah_g + g, &AhS[buf][chunk*512]);
      gload16(Al_g + g, &AlS[buf][chunk*512]);
    }
    #pragma unroll
    for (int c = 0; c < 2; ++c){
      const int chunk = wave*2 + c;
      const long g = bOff + (long)(nBase + chunk*16 + rsub)*ldb + k0 + cg8;
      gload16(Bh_g + g, &BhS[buf][chunk*512]);
    }
  };

  f32x4 acc[FM][FN] = {};

  stage(0, 0);
  __syncthreads();
  const int nk = K >> 5;
  for (int t = 0; t < nk; ++t){
    const int buf = t & 1;
    if (t + 1 < nk) stage(buf ^ 1, (t + 1) << 5);

    f16x8 ah[FM], al[FM], bh[FN];
    #pragma unroll
    for (int mi = 0; mi < FM; ++mi){
      const int off = (wm*WM + mi*16 + (lane & 15))*BK + (lane >> 4)*8;
      ah[mi] = *(const f16x8*)&AhS[buf][off];
      al[mi] = *(const f16x8*)&AlS[buf][off];
    }
    #pragma unroll
    for (int ni = 0; ni < FN; ++ni){
      const int off = (wn*WN + ni*16 + (lane & 15))*BK + (lane >> 4)*8;
      bh[ni] = *(const f16x8*)&BhS[buf][off];
    }
    #pragma unroll
    for (int mi = 0; mi < FM; ++mi)
      #pragma unroll
      for (int ni = 0; ni < FN; ++ni){
        acc[mi][ni] = __builtin_amdgcn_mfma_f32_16x16x32_f16(ah[mi], bh[ni], acc[mi][ni], 0, 0, 0);
        acc[mi][ni] = __builtin_amdgcn_mfma_f32_16x16x32_f16(al[mi], bh[ni], acc[mi][ni], 0, 0, 0);
      }
    __syncthreads();
  }

  const int cr = (lane >> 4) * 4, cc = lane & 15;
  #pragma unroll
  for (int mi = 0; mi < FM; ++mi)
    #pragma unroll
    for (int ni = 0; ni < FN; ++ni)
      #pragma unroll
      for (int r = 0; r < 4; ++r){
        const int row = mBase + wm*WM + mi*16 + cr + r;
        const int col = nBase + wn*WN + ni*16 + cc;
        float v = acc[mi][ni][r];
        if constexpr (EPI == 1){
          v *= scale;
          if (maskp[(long)b*Ssz + col]) v = -1e9f;
        }
        const long ci = cOff + (long)row*ldc + col;
        if constexpr (CM == 0){
          ((float*)Cp)[ci] = v;
        } else {
          u16 hh, ll;
          split1h(v, hh, ll);
          ((u16*)Cp)[ci]  = hh;
          ((u16*)Cp2)[ci] = ll;
        }
      }
}

// ---------------- row softmax (width 2048), fp32 in-place ----------------
__global__ __launch_bounds__(256)
void softmax_inplace(float* __restrict__ data, int Wd)
{
  float* rp = data + (long)blockIdx.x * Wd;
  const int tid = threadIdx.x;
  const int lane = tid & 63, wv = tid >> 6;
  f32x4 v0 = ((const f32x4*)rp)[tid*2];
  f32x4 v1 = ((const f32x4*)rp)[tid*2+1];
  float m = fmaxf(fmaxf(fmaxf(v0[0],v0[1]),fmaxf(v0[2],v0[3])),
                  fmaxf(fmaxf(v1[0],v1[1]),fmaxf(v1[2],v1[3])));
  #pragma unroll
  for (int off = 32; off; off >>= 1) m = fmaxf(m, __shfl_xor(m, off));
  __shared__ float rm[4], rs[4];
  if (lane == 0) rm[wv] = m;
  __syncthreads();
  m = fmaxf(fmaxf(rm[0],rm[1]), fmaxf(rm[2],rm[3]));
  f32x4 e0, e1;
  #pragma unroll
  for (int i = 0; i < 4; ++i){ e0[i] = __expf(v0[i]-m); e1[i] = __expf(v1[i]-m); }
  float s = (e0[0]+e0[1]+e0[2]+e0[3]) + (e1[0]+e1[1]+e1[2]+e1[3]);
  #pragma unroll
  for (int off = 32; off; off >>= 1) s += __shfl_xor(s, off);
  if (lane == 0) rs[wv] = s;
  __syncthreads();
  s = (rs[0]+rs[1]) + (rs[2]+rs[3]);
  const float inv = 1.0f / s;
  ((f32x4*)rp)[tid*2]   = e0 * inv;
  ((f32x4*)rp)[tid*2+1] = e1 * inv;
}

// ---------------- batched 64xK @ Kx64 einsum, fp32 A x f16 plane-pair B, split-K ----------------
__global__ __launch_bounds__(256)
void einsum64(const float* __restrict__ A,
              const u16* __restrict__ Bhip, const u16* __restrict__ Blop,
              float* __restrict__ Cpart,
              int K, int KC, int lda, int ldb,
              long aB, long aH, long bB, long bH, int H2, int nbatch)
{
  __shared__ float As[64][68];
  __shared__ float Bs[64][68];
  const int tid = threadIdx.x;
  const int kc = blockIdx.x, batch = blockIdx.y;
  const int b = batch / H2, h = batch - b*H2;
  const float* Ab = A + (long)b*aB + (long)h*aH;
  const u16* Bh = Bhip + (long)b*bB + (long)h*bH;
  const u16* Bl = Blop + (long)b*bB + (long)h*bH;
  const int kchunk = K / KC, kbeg = kc * kchunk;
  const int tm = tid >> 4, tn = tid & 15;
  const int sr = tid >> 4, sc = (tid & 15) * 4;
  float acc[4][4] = {};
  for (int ks = kbeg; ks < kbeg + kchunk; ks += 64){
    if (ks != kbeg) __syncthreads();
    #pragma unroll
    for (int p = 0; p < 4; ++p){
      const int g = p*16 + sr;
      f32x4 av = *(const f32x4*)&Ab[(long)g*lda + ks + sc];
      As[sc+0][g] = av[0]; As[sc+1][g] = av[1];
      As[sc+2][g] = av[2]; As[sc+3][g] = av[3];
      const int kr = p*16 + sr;
      ushort4 h4 = *(const ushort4*)&Bh[(long)(ks+kr)*ldb + sc];
      ushort4 l4 = *(const ushort4*)&Bl[(long)(ks+kr)*ldb + sc];
      Bs[kr][sc+0] = h2f(h4.x) + h2f(l4.x);
      Bs[kr][sc+1] = h2f(h4.y) + h2f(l4.y);
      Bs[kr][sc+2] = h2f(h4.z) + h2f(l4.z);
      Bs[kr][sc+3] = h2f(h4.w) + h2f(l4.w);
    }
    __syncthreads();
    #pragma unroll 8
    for (int k = 0; k < 64; ++k){
      f32x4 a4 = *(const f32x4*)&As[k][tm*4];
      f32x4 b4 = *(const f32x4*)&Bs[k][tn*4];
      #pragma unroll
      for (int i = 0; i < 4; ++i)
        #pragma unroll
        for (int j = 0; j < 4; ++j)
          acc[i][j] += a4[i] * b4[j];
    }
  }
  float* outp = Cpart + ((long)(kc*nbatch + batch) << 12);
  #pragma unroll
  for (int i = 0; i < 4; ++i){
    f32x4 v = { acc[i][0], acc[i][1], acc[i][2], acc[i][3] };
    *(f32x4*)&outp[(tm*4+i)*64 + tn*4] = v;
  }
}

// ---------------- dual einsum: shared A, two B plane-pairs (kk & vs) ----------------
__global__ __launch_bounds__(256)
void einsum64_dual(const float* __restrict__ A,
                   const u16* __restrict__ B1h, const u16* __restrict__ B1l,
                   const u16* __restrict__ B2h, const u16* __restrict__ B2l,
                   float* __restrict__ P1, float* __restrict__ P2,
                   int K, int KC, int lda, int ldb,
                   long aB, long aH, long bB, long bH, int H2, int nbatch)
{
  __shared__ float As[64][68];
  __shared__ float B1s[64][68];
  __shared__ float B2s[64][68];
  const int tid = threadIdx.x;
  const int kc = blockIdx.x, batch = blockIdx.y;
  const int b = batch / H2, h = batch - b*H2;
  const float* Ab = A + (long)b*aB + (long)h*aH;
  const u16* b1h = B1h + (long)b*bB + (long)h*bH;
  const u16* b1l = B1l + (long)b*bB + (long)h*bH;
  const u16* b2h = B2h + (long)b*bB + (long)h*bH;
  const u16* b2l = B2l + (long)b*bB + (long)h*bH;
  const int kchunk = K / KC, kbeg = kc * kchunk;
  const int tm = tid >> 4, tn = tid & 15;
  const int sr = tid >> 4, sc = (tid & 15) * 4;
  float acc1[4][4] = {}, acc2[4][4] = {};
  for (int ks = kbeg; ks < kbeg + kchunk; ks += 64){
    if (ks != kbeg) __syncthreads();
    #pragma unroll
    for (int p = 0; p < 4; ++p){
      const int g = p*16 + sr;
      f32x4 av = *(const f32x4*)&Ab[(long)g*lda + ks + sc];
      As[sc+0][g] = av[0]; As[sc+1][g] = av[1];
      As[sc+2][g] = av[2]; As[sc+3][g] = av[3];
      const int kr = p*16 + sr;
      ushort4 h4 = *(const ushort4*)&b1h[(long)(ks+kr)*ldb + sc];
      ushort4 l4 = *(const ushort4*)&b1l[(long)(ks+kr)*ldb + sc];
      B1s[kr][sc+0] = h2f(h4.x) + h2f(l4.x);
      B1s[kr][sc+1] = h2f(h4.y) + h2f(l4.y);
      B1s[kr][sc+2] = h2f(h4.z) + h2f(l4.z);
      B1s[kr][sc+3] = h2f(h4.w) + h2f(l4.w);
      h4 = *(const ushort4*)&b2h[(long)(ks+kr)*ldb + sc];
      l4 = *(const ushort4*)&b2l[(long)(ks+kr)*ldb + sc];
      B2s[kr][sc+0] = h2f(h4.x) + h2f(l4.x);
      B2s[kr][sc+1] = h2f(h4.y) + h2f(l4.y);
      B2s[kr][sc+2] = h2f(h4.z) + h2f(l4.z);
      B2s[kr][sc+3] = h2f(h4.w) + h2f(l4.w);
    }
    __syncthreads();
    #pragma unroll 4
    for (int k = 0; k < 64; ++k){
      f32x4 a4 = *(const f32x4*)&As[k][tm*4];
      f32x4 b4 = *(const f32x4*)&B1s[k][tn*4];
      f32x4 c4 = *(const f32x4*)&B2s[k][tn*4];
      #pragma unroll
      for (int i = 0; i < 4; ++i)
        #pragma unroll
        for (int j = 0; j < 4; ++j){
          acc1[i][j] += a4[i] * b4[j];
          acc2[i][j] += a4[i] * c4[j];
        }
    }
  }
  const long po = ((long)(kc*nbatch + batch) << 12);
  #pragma unroll
  for (int i = 0; i < 4; ++i){
    f32x4 v1 = { acc1[i][0], acc1[i][1], acc1[i][2], acc1[i][3] };
    f32x4 v2 = { acc2[i][0], acc2[i][1], acc2[i][2], acc2[i][3] };
    *(f32x4*)&P1[po + (tm*4+i)*64 + tn*4] = v1;
    *(f32x4*)&P2[po + (tm*4+i)*64 + tn*4] = v2;
  }
}

// ---------------- sum split-K partials -> split f16 planes ----------------
__global__ __launch_bounds__(256)
void reduce64(const float* __restrict__ part,
              u16* __restrict__ outhi, u16* __restrict__ outlo,
              int n4, int parts)
{
  const int idx = blockIdx.x*256 + threadIdx.x;
  if (idx >= n4) return;
  f32x4 s = ((const f32x4*)part)[idx];
  for (int p = 1; p < parts; ++p) s += ((const f32x4*)part)[(long)p*n4 + idx];
  ushort4 uh, ul;
  split1h(s[0], uh.x, ul.x); split1h(s[1], uh.y, ul.y);
  split1h(s[2], uh.z, ul.z); split1h(s[3], uh.w, ul.w);
  ((ushort4*)outhi)[idx] = uh;
  ((ushort4*)outlo)[idx] = ul;
}

// ---------------- stage 2, MFMA: S=qs@gk^T -> softmax(G=64) -> l_attn; O=P@gv -> attn planes ----
__global__ __launch_bounds__(256)
void stage2_mfma(const u16* __restrict__ qhi, const u16* __restrict__ qlo,
                 const u16* __restrict__ gkh_g, const u16* __restrict__ gkl_g,
                 const u16* __restrict__ gvh_g, const u16* __restrict__ gvl_g,
                 float* __restrict__ lattn, u16* __restrict__ ahi, u16* __restrict__ alo,
                 float scale)
{
  __shared__ __align__(16) u16 Ah[128][72];
  __shared__ __align__(16) u16 Al[128][72];
  __shared__ __align__(16) u16 Bh[64][72];
  __shared__ __align__(16) u16 Bl[64][72];
  const int tid = threadIdx.x;
  const int bh = blockIdx.y;
  const int b = bh >> 4, h = bh & 15;
  const int l0 = blockIdx.x * 128;
  const int wm = tid >> 6, lane = tid & 63;

  const long qbase = ((long)b*2048 + l0)*1024 + h*64;
  #pragma unroll
  for (int it = 0; it < 4; ++it){
    const int e = it*256 + tid, row = e >> 3, s = e & 7;
    const long g = qbase + (long)row*1024 + s*8;
    *(uint4*)&Ah[row][s*8] = *(const uint4*)(qhi + g);
    *(uint4*)&Al[row][s*8] = *(const uint4*)(qlo + g);
  }
  const long gb = (long)bh * 4096;
  #pragma unroll
  for (int it = 0; it < 2; ++it){
    const int e = it*256 + tid, gr = e >> 3, s = e & 7;
    *(uint4*)&Bh[gr][s*8] = *(const uint4*)(gkh_g + gb + gr*64 + s*8);
    *(uint4*)&Bl[gr][s*8] = *(const uint4*)(gkl_g + gb + gr*64 + s*8);
  }
  __syncthreads();

  f32x4 acc[2][4] = {};
  #pragma unroll
  for (int k0 = 0; k0 < 64; k0 += 32){
    f16x8 a_h[2], a_l[2], b_h[4], b_l[4];
    #pragma unroll
    for (int mi = 0; mi < 2; ++mi){
      const int row = wm*32 + mi*16 + (lane & 15);
      a_h[mi] = *(const f16x8*)&Ah[row][k0 + (lane >> 4)*8];
      a_l[mi] = *(const f16x8*)&Al[row][k0 + (lane >> 4)*8];
    }
    #pragma unroll
    for (int ni = 0; ni < 4; ++ni){
      const int nr = ni*16 + (lane & 15);
      b_h[ni] = *(const f16x8*)&Bh[nr][k0 + (lane >> 4)*8];
      b_l[ni] = *(const f16x8*)&Bl[nr][k0 + (lane >> 4)*8];
    }
    #pragma unroll
    for (int mi = 0; mi < 2; ++mi)
      #pragma unroll
      for (int ni = 0; ni < 4; ++ni){
        acc[mi][ni] = __builtin_amdgcn_mfma_f32_16x16x32_f16(a_h[mi], b_h[ni], acc[mi][ni], 0, 0, 0);
        acc[mi][ni] = __builtin_amdgcn_mfma_f32_16x16x32_f16(a_l[mi], b_h[ni], acc[mi][ni], 0, 0, 0);
        acc[mi][ni] = __builtin_amdgcn_mfma_f32_16x16x32_f16(a_h[mi], b_l[ni], acc[mi][ni], 0, 0, 0);
      }
  }
  __syncthreads();

  #pragma unroll
  for (int it = 0; it < 4; ++it){
    const int e = it*256 + tid;
    const int gr = e >> 4, d0 = (e & 15) * 4;
    ushort4 vh = *(const ushort4*)(gvh_g + gb + gr*64 + d0);
    ushort4 vl = *(const ushort4*)(gvl_g + gb + gr*64 + d0);
    Bh[d0+0][gr] = vh.x; Bh[d0+1][gr] = vh.y; Bh[d0+2][gr] = vh.z; Bh[d0+3][gr] = vh.w;
    Bl[d0+0][gr] = vl.x; Bl[d0+1][gr] = vl.y; Bl[d0+2][gr] = vl.z; Bl[d0+3][gr] = vl.w;
  }

  #pragma unroll
  for (int mi = 0; mi < 2; ++mi){
    #pragma unroll
    for (int r = 0; r < 4; ++r){
      float v0 = acc[mi][0][r]*scale, v1 = acc[mi][1][r]*scale;
      float v2 = acc[mi][2][r]*scale, v3 = acc[mi][3][r]*scale;
      float mx = fmaxf(fmaxf(v0,v1), fmaxf(v2,v3));
      #pragma unroll
      for (int off = 1; off < 16; off <<= 1) mx = fmaxf(mx, __shfl_xor(mx, off, 16));
      float e0 = __expf(v0-mx), e1 = __expf(v1-mx), e2 = __expf(v2-mx), e3 = __expf(v3-mx);
      float sum = (e0+e1) + (e2+e3);
      #pragma unroll
      for (int off = 1; off < 16; off <<= 1) sum += __shfl_xor(sum, off, 16);
      const float inv = 1.0f / sum;
      e0 *= inv; e1 *= inv; e2 *= inv; e3 *= inv;
      const int lrow = wm*32 + mi*16 + (lane >> 4)*4 + r;
      float* lp = lattn + ((long)bh*2048 + l0 + lrow)*64 + (lane & 15);
      lp[0] = e0; lp[16] = e1; lp[32] = e2; lp[48] = e3;
      u16 hh, ll;
      split1h(e0, hh, ll); Ah[lrow][ 0 + (lane&15)] = hh; Al[lrow][ 0 + (lane&15)] = ll;
      split1h(e1, hh, ll); Ah[lrow][16 + (lane&15)] = hh; Al[lrow][16 + (lane&15)] = ll;
      split1h(e2, hh, ll); Ah[lrow][32 + (lane&15)] = hh; Al[lrow][32 + (lane&15)] = ll;
      split1h(e3, hh, ll); Ah[lrow][48 + (lane&15)] = hh; Al[lrow][48 + (lane&15)] = ll;
    }
  }
  __syncthreads();

  f32x4 o[2][4] = {};
  #pragma unroll
  for (int k0 = 0; k0 < 64; k0 += 32){
    f16x8 p_h[2], p_l[2], b_h[4], b_l[4];
    #pragma unroll
    for (int mi = 0; mi < 2; ++mi){
      const int row = wm*32 + mi*16 + (lane & 15);
      p_h[mi] = *(const f16x8*)&Ah[row][k0 + (lane >> 4)*8];
      p_l[mi] = *(const f16x8*)&Al[row][k0 + (lane >> 4)*8];
    }
    #pragma unroll
    for (int ni = 0; ni < 4; ++ni){
      const int nr = ni*16 + (lane & 15);
      b_h[ni] = *(const f16x8*)&Bh[nr][k0 + (lane >> 4)*8];
      b_l[ni] = *(const f16x8*)&Bl[nr][k0 + (lane >> 4)*8];
    }
    #pragma unroll
    for (int mi = 0; mi < 2; ++mi)
      #pragma unroll
      for (int ni = 0; ni < 4; ++ni){
        o[mi][ni] = __builtin_amdgcn_mfma_f32_16x16x32_f16(p_h[mi], b_h[ni], o[mi][ni], 0, 0, 0);
        o[mi][ni] = __builtin_amdgcn_mfma_f32_16x16x32_f16(p_l[mi], b_h[ni], o[mi][ni], 0, 0, 0);
        o[mi][ni] = __builtin_amdgcn_mfma_f32_16x16x32_f16(p_h[mi], b_l[ni], o[mi][ni], 0, 0, 0);
      }
  }

  #pragma unroll
  for (int mi = 0; mi < 2; ++mi)
    #pragma unroll
    for (int ni = 0; ni < 4; ++ni)
      #pragma unroll
      for (int r = 0; r < 4; ++r){
        const int lrow = wm*32 + mi*16 + (lane >> 4)*4 + r;
        const int d = ni*16 + (lane & 15);
        u16 hh, ll;
        split1h(o[mi][ni][r], hh, ll);
        const long oidx = ((long)b*2048 + l0 + lrow)*1024 + h*64 + d;
        ahi[oidx] = hh; alo[oidx] = ll;
      }
}

extern "C" void kernel_launch(void* const* d_in, const int* in_sizes, int n_in,
                              void* d_out, int out_size, void* d_ws, size_t ws_size,
                              hipStream_t stream)
{
  const float* query = (const float*)d_in[0];
  const float* key   = (const float*)d_in[1];
  const float* value = (const float*)d_in[2];
  const unsigned char* mask_raw = (const unsigned char*)d_in[4];
  const float* Wq = (const float*)d_in[6];
  const float* Wk = (const float*)d_in[7];
  const float* Wv = (const float*)d_in[8];
  const float* Wi = (const float*)d_in[9];
  const float* Wo = (const float*)d_in[10];
  float* out0 = (float*)d_out;                  // (B,L,E)
  float* out1 = out0 + 16777216;                // (B,H,L,G)

  // ---- workspace: W[0,20) | R1[20,84) | R2 qs[84,148) | R3 vs[148,212) | R4[212,276) MiB ----
  char* ws = (char*)d_ws;
  u16* WoT_hi = (u16*)(ws + 0);
  u16* WqT_hi = (u16*)(ws + (4L<<20));
  u16* WkT_hi = (u16*)(ws + (8L<<20));
  u16* WvT_hi = (u16*)(ws + (12L<<20));
  u16* WiT_hi = (u16*)(ws + (16L<<20));
  u16* WiT_lo = (u16*)(ws + (18L<<20));
  // R1: qp -> kp -> vp -> g_scores/g_attn (time-shared)
  u16* qp_hi = (u16*)(ws + (20L<<20));
  u16* qp_lo = (u16*)(ws + (52L<<20));
  u16* kp_hi = qp_hi;  u16* kp_lo = qp_lo;
  u16* vp_hi = qp_hi;  u16* vp_lo = qp_lo;
  float* gsc  = (float*)(ws + (20L<<20));       // g_scores/g_attn fp32 (64 MiB)
  // R2: qs planes
  u16* qs_hi  = (u16*)(ws + (84L<<20));
  u16* qs_lo  = (u16*)(ws + (116L<<20));
  // R3: vs planes
  u16* vs_hi  = (u16*)(ws + (148L<<20));
  u16* vs_lo  = (u16*)(ws + (180L<<20));
  // R4: ips-scores/wts -> kk planes -> attn planes
  float* ips  = (float*)(ws + (212L<<20));
  u16* kk_hi  = (u16*)(ws + (212L<<20));
  u16* kk_lo  = (u16*)(ws + (244L<<20));
  u16* attn_hi = kk_hi;
  u16* attn_lo = kk_lo;
  // small overlays on dead W planes:
  float* part1 = (float*)(ws + (4L<<20));       // WqT region, dead after qs-proj
  float* part2 = (float*)(ws + (12L<<20));      // WvT region, dead after vs-proj
  u16* gk_hi = (u16*)(ws + (8L<<20));           // WkT region, dead after kk-proj
  u16* gk_lo = (u16*)(ws + (9L<<20));
  u16* gv_hi = (u16*)(ws + (10L<<20));
  u16* gv_lo = (u16*)(ws + (11L<<20));
  unsigned char* mask_ws = (unsigned char*)(ws + (16L<<20)); // WiT_hi head, dead after ips
  u16* gqs_hi = (u16*)(ws + (17L<<20));
  u16* gqs_lo = (u16*)(ws + (18L<<20));         // (WiT_lo region, dead after ips)

  const dim3 blk(256);
  const float scale = 0.125f;   // 1/sqrt(64)

  // 1) weight transposes -> f16 planes (lo only for Wi, the only 2-term weight-A)
  transpose_split<<<dim3(16,16), blk, 0, stream>>>(Wq, WqT_hi, nullptr, 1024, 1024);
  transpose_split<<<dim3(16,16), blk, 0, stream>>>(Wk, WkT_hi, nullptr, 1024, 1024);
  transpose_split<<<dim3(16,16), blk, 0, stream>>>(Wv, WvT_hi, nullptr, 1024, 1024);
  transpose_split<<<dim3(16,16), blk, 0, stream>>>(Wi, WiT_hi, WiT_lo, 1024, 1024);
  transpose_split<<<dim3(16,16), blk, 0, stream>>>(Wo, WoT_hi, nullptr, 1024, 1024);

  // 2) query -> planes (R1)
  conv_split<<<8192, blk, 0, stream>>>(query, qp_hi, qp_lo, 2097152);

  // 3) qs-proj: A=qp planes, B=WqT_hi -> qs planes (R2)
  gemm_g<128,1,0><<<dim3(8,128,1), blk, 0, stream>>>(
      qp_hi, qp_lo, WqT_hi, qs_hi, qs_lo, nullptr,
      1024, 1024,1024,1024, 0,0, 0,0, 0,0, 1, 2048, 1.f);

  // 4) ips: A=WiT planes, B=qp_hi -> fp32 (R4)
  gemm_g<128,0,0><<<dim3(16,8,8), blk, 0, stream>>>(
      WiT_hi, WiT_lo, qp_hi, ips, nullptr, nullptr,
      1024, 1024,1024,2048, 0,0, 2097152L,0, 2097152L,0, 1, 2048, 1.f);
  mask_norm<<<1, blk, 0, stream>>>(mask_raw, mask_ws, 16384);
  softmax_inplace<<<8192, blk, 0, stream>>>(ips, 2048);

  // 5) gqs[bh] = wts[bh](64xL) @ qs[bh](Lx64) -> planes (part1 on dead WqT)
  einsum64<<<dim3(2,128), blk, 0, stream>>>(ips, qs_hi, qs_lo, part1,
      2048, 2, 2048, 1024, 2097152L, 131072L, 2097152L, 64L, 16, 128);
  reduce64<<<512, blk, 0, stream>>>(part1, gqs_hi, gqs_lo, 131072, 2);

  // 6) key -> planes (R1, qp dead); kk-proj -> kk planes (R4, wts dead)
  conv_split<<<8192, blk, 0, stream>>>(key, kp_hi, kp_lo, 2097152);
  gemm_g<128,1,0><<<dim3(8,128,1), blk, 0, stream>>>(
      kp_hi, kp_lo, WkT_hi, kk_hi, kk_lo, nullptr,
      1024, 1024,1024,1024, 0,0, 0,0, 0,0, 1, 2048, 1.f);

  // 7) value -> planes (R1, kp dead); vs-proj -> vs planes (R3)
  conv_split<<<8192, blk, 0, stream>>>(value, vp_hi, vp_lo, 2097152);
  gemm_g<128,1,0><<<dim3(8,128,1), blk, 0, stream>>>(
      vp_hi, vp_lo, WvT_hi, vs_hi, vs_lo, nullptr,
      1024, 1024,1024,1024, 0,0, 0,0, 0,0, 1, 2048, 1.f);

  // 8) g_scores[bh] = gqs@kk^T * scale, mask -> fp32 (R1, vp dead); softmax -> g_attn
  gemm_g<64,0,1><<<dim3(16,1,128), blk, 0, stream>>>(
      gqs_hi, gqs_lo, kk_hi, gsc, nullptr, mask_ws,
      64, 64,1024,2048, 65536L,4096L, 2097152L,64L, 2097152L,131072L, 16, 2048, scale);
  softmax_inplace<<<8192, blk, 0, stream>>>(gsc, 2048);

  // 9) gk/gv[bh] = g_attn @ {kk,vs} -> planes (overlays on dead WkT/WvT)
  einsum64_dual<<<dim3(2,128), blk, 0, stream>>>(gsc, kk_hi, kk_lo, vs_hi, vs_lo,
      part1, part2, 2048, 2, 2048, 1024, 2097152L, 131072L, 2097152L, 64L, 16, 128);
  reduce64<<<512, blk, 0, stream>>>(part1, gk_hi, gk_lo, 131072, 2);
  reduce64<<<512, blk, 0, stream>>>(part2, gv_hi, gv_lo, 131072, 2);

  // 10) stage 2 (MFMA): l_attn (out1) + attn planes (R4, kk dead)
  stage2_mfma<<<dim3(16,128), blk, 0, stream>>>(qs_hi, qs_lo, gk_hi, gk_lo,
      gv_hi, gv_lo, out1, attn_hi, attn_lo, scale);

  // 11) out0 = attn @ Wo
  gemm_g<128,0,0><<<dim3(8,128,1), blk, 0, stream>>>(
      attn_hi, attn_lo, WoT_hi, out0, nullptr, nullptr,
      1024, 1024,1024,1024, 0,0, 0,0, 0,0, 1, 2048, 1.f);

  (void)in_sizes; (void)n_in; (void)out_size; (void)ws_size;
}

// Round 7
// 624.490 us; speedup vs baseline: 1.4196x; 1.4196x over previous
//
#include <hip/hip_runtime.h>

// EGA multi-headed attention, MI355X/gfx950.
// Round 7: big GEMMs -> f16 1-term (A hi only; B was already hi-only) + XCD-
//          chunked block swizzle. g_scores stays 2-term; einsums/stage2 keep
//          hi+lo reconstruction. global_load_lds dbuf staging as r6.
// Dims fixed: B=8, L=S=2048, E=1024, H=16, G=64, Ek=Ev=64, KD=VD=1024.

typedef float f32x4 __attribute__((ext_vector_type(4)));
typedef _Float16 f16x8 __attribute__((ext_vector_type(8)));
typedef unsigned short u16;

#define DEV static __device__ __forceinline__

DEV u16 f2h(float x){
  _Float16 h = (_Float16)x;
  return __builtin_bit_cast(u16, h);
}
DEV float h2f(u16 u){
  return (float)__builtin_bit_cast(_Float16, u);
}
DEV void split1h(float x, u16 &h, u16 &l){
  h = f2h(x);
  l = f2h(x - h2f(h));
}
DEV unsigned pk2h(float a, float b){
  return (unsigned)f2h(a) | ((unsigned)f2h(b) << 16);
}

// async global->LDS, 16B per lane; dst is wave-uniform base (HW adds lane*16)
DEV void gload16(const u16* src, u16* dst_lds){
  __builtin_amdgcn_global_load_lds(
      (__attribute__((address_space(1))) void*)src,
      (__attribute__((address_space(3))) void*)dst_lds, 16, 0, 0);
}

// ---------------- mask dtype sniff + normalize to uchar ----------------
__global__ __launch_bounds__(256)
void mask_norm(const unsigned char* __restrict__ src, unsigned char* __restrict__ dst, int n)
{
  const unsigned* w = (const unsigned*)src;
  const int tid = threadIdx.x;
  int local = 0;
  for (int i = tid; i < n/4; i += 256){
    unsigned v = w[i];
    if (v == 0x3F800000u) local |= 2;
    else if (v > 1u)      local |= 1;
  }
  __shared__ int red[256];
  red[tid] = local;
  __syncthreads();
  for (int s = 128; s; s >>= 1){
    if (tid < s) red[tid] |= red[tid+s];
    __syncthreads();
  }
  const int r = red[0];
  const int mode = (r & 2) ? 2 : ((r & 1) ? 1 : 0);   // 2=f32, 1=u8, 0=i32
  for (int i = tid; i < n; i += 256){
    unsigned char v;
    if (mode == 1) v = src[i] ? 1 : 0;
    else           v = w[i]   ? 1 : 0;
    dst[i] = v;
  }
}

// ---------------- fp32 -> f16 hi plane only (8 elems/thread) ----------------
__global__ __launch_bounds__(256)
void conv_hi(const float* __restrict__ x, u16* __restrict__ hi, int n8)
{
  const int i = blockIdx.x*256 + threadIdx.x;
  if (i >= n8) return;
  f32x4 a = ((const f32x4*)x)[2*i], b = ((const f32x4*)x)[2*i+1];
  uint4 uh;
  uh.x = pk2h(a[0], a[1]); uh.y = pk2h(a[2], a[3]);
  uh.z = pk2h(b[0], b[1]); uh.w = pk2h(b[2], b[3]);
  ((uint4*)hi)[i] = uh;
}

// ---------------- 1024x1024 transpose, fp32 -> f16 hi plane ----------------
__global__ __launch_bounds__(256)
void transpose_hi(const float* __restrict__ Wsrc, u16* __restrict__ Whi, int Kd, int Nd)
{
  __shared__ float t[64][65];
  const int tid = threadIdx.x;
  const int n0 = blockIdx.x * 64, k0 = blockIdx.y * 64;
  #pragma unroll
  for (int it = 0; it < 16; ++it){
    int e = it*256 + tid, r = e >> 6, c = e & 63;
    t[r][c] = Wsrc[(long)(k0+r)*Nd + (n0+c)];
  }
  __syncthreads();
  #pragma unroll
  for (int it = 0; it < 16; ++it){
    int e = it*256 + tid, r = e >> 6, c = e & 63;
    Whi[(long)(n0+r)*Kd + (k0+c)] = f2h(t[c][r]);
  }
}

// ---------------- f16 MFMA GEMM, global_load_lds staging, dbuf ----------------
// C[m,n] = sum_k A[m,k]*Bt[n,k].  TERMS=1: A=hi; TERMS=2: A=hi+lo. B=hi.
// CM: 0 = fp32 out; 1 = split f16 planes out.  EPI==1: scale+mask epilogue.
// SWZ: XCD-chunked bijective block swizzle (requires nwg%8==0, gridDim.z==1).
template<int TM, int TERMS, int CM, int EPI, int SWZ>
__global__ __launch_bounds__(256)
void gemm_g(const u16* __restrict__ Ah_g, const u16* __restrict__ Al_g,
            const u16* __restrict__ Bh_g,
            void* __restrict__ Cp, void* __restrict__ Cp2,
            const unsigned char* __restrict__ maskp,
            int K, int lda, int ldb, int ldc,
            long aB, long aH, long bB, long bH, long cB, long cH,
            int H2, int Ssz, float scale)
{
  constexpr int BN = 128, BK = 32;
  constexpr int WM = TM/2, WN = BN/2;
  constexpr int FM = WM/16, FN = WN/16;
  __shared__ __align__(16) u16 AhS[2][TM*BK];
  __shared__ __align__(16) u16 AlS[2][TERMS == 2 ? TM*BK : 8];
  __shared__ __align__(16) u16 BhS[2][BN*BK];

  const int tid = threadIdx.x;
  int bx = blockIdx.x, by = blockIdx.y;
  if constexpr (SWZ){
    const int gx = gridDim.x;
    const int nwg = gx * gridDim.y;
    const int q = nwg >> 3;
    const int flat = bx + gx * by;
    const int nf = (flat & 7) * q + (flat >> 3);
    bx = nf % gx; by = nf / gx;
  }
  const int batch = blockIdx.z;
  const int b = batch / H2, h = batch - b*H2;
  const long aOff = (long)b*aB + (long)h*aH;
  const long bOff = (long)b*bB + (long)h*bH;
  const long cOff = (long)b*cB + (long)h*cH;
  const int nBase = bx * BN;
  const int mBase = by * TM;
  const int wave = tid >> 6, lane = tid & 63;
  const int wm = wave >> 1, wn = wave & 1;
  const int cg8 = (lane & 3) * 8;
  const int rsub = lane >> 2;

  auto stage = [&](int buf, int k0){
    #pragma unroll
    for (int c = 0; c < TM/64; ++c){
      const int chunk = wave*(TM/64) + c;
      const long g = aOff + (long)(mBase + chunk*16 + rsub)*lda + k0 + cg8;
      gload16(Ah_g + g, &AhS[buf][chunk*512]);
      if constexpr (TERMS == 2) gload16(Al_g + g, &AlS[buf][chunk*512]);
    }
    #pragma unroll
    for (int c = 0; c < 2; ++c){
      const int chunk = wave*2 + c;
      const long g = bOff + (long)(nBase + chunk*16 + rsub)*ldb + k0 + cg8;
      gload16(Bh_g + g, &BhS[buf][chunk*512]);
    }
  };

  f32x4 acc[FM][FN] = {};

  stage(0, 0);
  __syncthreads();
  const int nk = K >> 5;
  for (int t = 0; t < nk; ++t){
    const int buf = t & 1;
    if (t + 1 < nk) stage(buf ^ 1, (t + 1) << 5);

    f16x8 ah[FM], al[FM], bh[FN];
    #pragma unroll
    for (int mi = 0; mi < FM; ++mi){
      const int off = (wm*WM + mi*16 + (lane & 15))*BK + (lane >> 4)*8;
      ah[mi] = *(const f16x8*)&AhS[buf][off];
      if constexpr (TERMS == 2) al[mi] = *(const f16x8*)&AlS[buf][off];
    }
    #pragma unroll
    for (int ni = 0; ni < FN; ++ni){
      const int off = (wn*WN + ni*16 + (lane & 15))*BK + (lane >> 4)*8;
      bh[ni] = *(const f16x8*)&BhS[buf][off];
    }
    #pragma unroll
    for (int mi = 0; mi < FM; ++mi)
      #pragma unroll
      for (int ni = 0; ni < FN; ++ni){
        acc[mi][ni] = __builtin_amdgcn_mfma_f32_16x16x32_f16(ah[mi], bh[ni], acc[mi][ni], 0, 0, 0);
        if constexpr (TERMS == 2)
          acc[mi][ni] = __builtin_amdgcn_mfma_f32_16x16x32_f16(al[mi], bh[ni], acc[mi][ni], 0, 0, 0);
      }
    __syncthreads();
  }

  const int cr = (lane >> 4) * 4, cc = lane & 15;
  #pragma unroll
  for (int mi = 0; mi < FM; ++mi)
    #pragma unroll
    for (int ni = 0; ni < FN; ++ni)
      #pragma unroll
      for (int r = 0; r < 4; ++r){
        const int row = mBase + wm*WM + mi*16 + cr + r;
        const int col = nBase + wn*WN + ni*16 + cc;
        float v = acc[mi][ni][r];
        if constexpr (EPI == 1){
          v *= scale;
          if (maskp[(long)b*Ssz + col]) v = -1e9f;
        }
        const long ci = cOff + (long)row*ldc + col;
        if constexpr (CM == 0){
          ((float*)Cp)[ci] = v;
        } else {
          u16 hh, ll;
          split1h(v, hh, ll);
          ((u16*)Cp)[ci]  = hh;
          ((u16*)Cp2)[ci] = ll;
        }
      }
}

// ---------------- row softmax (width 2048), fp32 in-place ----------------
__global__ __launch_bounds__(256)
void softmax_inplace(float* __restrict__ data, int Wd)
{
  float* rp = data + (long)blockIdx.x * Wd;
  const int tid = threadIdx.x;
  const int lane = tid & 63, wv = tid >> 6;
  f32x4 v0 = ((const f32x4*)rp)[tid*2];
  f32x4 v1 = ((const f32x4*)rp)[tid*2+1];
  float m = fmaxf(fmaxf(fmaxf(v0[0],v0[1]),fmaxf(v0[2],v0[3])),
                  fmaxf(fmaxf(v1[0],v1[1]),fmaxf(v1[2],v1[3])));
  #pragma unroll
  for (int off = 32; off; off >>= 1) m = fmaxf(m, __shfl_xor(m, off));
  __shared__ float rm[4], rs[4];
  if (lane == 0) rm[wv] = m;
  __syncthreads();
  m = fmaxf(fmaxf(rm[0],rm[1]), fmaxf(rm[2],rm[3]));
  f32x4 e0, e1;
  #pragma unroll
  for (int i = 0; i < 4; ++i){ e0[i] = __expf(v0[i]-m); e1[i] = __expf(v1[i]-m); }
  float s = (e0[0]+e0[1]+e0[2]+e0[3]) + (e1[0]+e1[1]+e1[2]+e1[3]);
  #pragma unroll
  for (int off = 32; off; off >>= 1) s += __shfl_xor(s, off);
  if (lane == 0) rs[wv] = s;
  __syncthreads();
  s = (rs[0]+rs[1]) + (rs[2]+rs[3]);
  const float inv = 1.0f / s;
  ((f32x4*)rp)[tid*2]   = e0 * inv;
  ((f32x4*)rp)[tid*2+1] = e1 * inv;
}

// ---------------- batched 64xK @ Kx64 einsum, fp32 A x f16 plane-pair B, split-K ----------------
__global__ __launch_bounds__(256)
void einsum64(const float* __restrict__ A,
              const u16* __restrict__ Bhip, const u16* __restrict__ Blop,
              float* __restrict__ Cpart,
              int K, int KC, int lda, int ldb,
              long aB, long aH, long bB, long bH, int H2, int nbatch)
{
  __shared__ float As[64][68];
  __shared__ float Bs[64][68];
  const int tid = threadIdx.x;
  const int kc = blockIdx.x, batch = blockIdx.y;
  const int b = batch / H2, h = batch - b*H2;
  const float* Ab = A + (long)b*aB + (long)h*aH;
  const u16* Bh = Bhip + (long)b*bB + (long)h*bH;
  const u16* Bl = Blop + (long)b*bB + (long)h*bH;
  const int kchunk = K / KC, kbeg = kc * kchunk;
  const int tm = tid >> 4, tn = tid & 15;
  const int sr = tid >> 4, sc = (tid & 15) * 4;
  float acc[4][4] = {};
  for (int ks = kbeg; ks < kbeg + kchunk; ks += 64){
    if (ks != kbeg) __syncthreads();
    #pragma unroll
    for (int p = 0; p < 4; ++p){
      const int g = p*16 + sr;
      f32x4 av = *(const f32x4*)&Ab[(long)g*lda + ks + sc];
      As[sc+0][g] = av[0]; As[sc+1][g] = av[1];
      As[sc+2][g] = av[2]; As[sc+3][g] = av[3];
      const int kr = p*16 + sr;
      ushort4 h4 = *(const ushort4*)&Bh[(long)(ks+kr)*ldb + sc];
      ushort4 l4 = *(const ushort4*)&Bl[(long)(ks+kr)*ldb + sc];
      Bs[kr][sc+0] = h2f(h4.x) + h2f(l4.x);
      Bs[kr][sc+1] = h2f(h4.y) + h2f(l4.y);
      Bs[kr][sc+2] = h2f(h4.z) + h2f(l4.z);
      Bs[kr][sc+3] = h2f(h4.w) + h2f(l4.w);
    }
    __syncthreads();
    #pragma unroll 8
    for (int k = 0; k < 64; ++k){
      f32x4 a4 = *(const f32x4*)&As[k][tm*4];
      f32x4 b4 = *(const f32x4*)&Bs[k][tn*4];
      #pragma unroll
      for (int i = 0; i < 4; ++i)
        #pragma unroll
        for (int j = 0; j < 4; ++j)
          acc[i][j] += a4[i] * b4[j];
    }
  }
  float* outp = Cpart + ((long)(kc*nbatch + batch) << 12);
  #pragma unroll
  for (int i = 0; i < 4; ++i){
    f32x4 v = { acc[i][0], acc[i][1], acc[i][2], acc[i][3] };
    *(f32x4*)&outp[(tm*4+i)*64 + tn*4] = v;
  }
}

// ---------------- dual einsum: shared A, two B plane-pairs (kk & vs) ----------------
__global__ __launch_bounds__(256)
void einsum64_dual(const float* __restrict__ A,
                   const u16* __restrict__ B1h, const u16* __restrict__ B1l,
                   const u16* __restrict__ B2h, const u16* __restrict__ B2l,
                   float* __restrict__ P1, float* __restrict__ P2,
                   int K, int KC, int lda, int ldb,
                   long aB, long aH, long bB, long bH, int H2, int nbatch)
{
  __shared__ float As[64][68];
  __shared__ float B1s[64][68];
  __shared__ float B2s[64][68];
  const int tid = threadIdx.x;
  const int kc = blockIdx.x, batch = blockIdx.y;
  const int b = batch / H2, h = batch - b*H2;
  const float* Ab = A + (long)b*aB + (long)h*aH;
  const u16* b1h = B1h + (long)b*bB + (long)h*bH;
  const u16* b1l = B1l + (long)b*bB + (long)h*bH;
  const u16* b2h = B2h + (long)b*bB + (long)h*bH;
  const u16* b2l = B2l + (long)b*bB + (long)h*bH;
  const int kchunk = K / KC, kbeg = kc * kchunk;
  const int tm = tid >> 4, tn = tid & 15;
  const int sr = tid >> 4, sc = (tid & 15) * 4;
  float acc1[4][4] = {}, acc2[4][4] = {};
  for (int ks = kbeg; ks < kbeg + kchunk; ks += 64){
    if (ks != kbeg) __syncthreads();
    #pragma unroll
    for (int p = 0; p < 4; ++p){
      const int g = p*16 + sr;
      f32x4 av = *(const f32x4*)&Ab[(long)g*lda + ks + sc];
      As[sc+0][g] = av[0]; As[sc+1][g] = av[1];
      As[sc+2][g] = av[2]; As[sc+3][g] = av[3];
      const int kr = p*16 + sr;
      ushort4 h4 = *(const ushort4*)&b1h[(long)(ks+kr)*ldb + sc];
      ushort4 l4 = *(const ushort4*)&b1l[(long)(ks+kr)*ldb + sc];
      B1s[kr][sc+0] = h2f(h4.x) + h2f(l4.x);
      B1s[kr][sc+1] = h2f(h4.y) + h2f(l4.y);
      B1s[kr][sc+2] = h2f(h4.z) + h2f(l4.z);
      B1s[kr][sc+3] = h2f(h4.w) + h2f(l4.w);
      h4 = *(const ushort4*)&b2h[(long)(ks+kr)*ldb + sc];
      l4 = *(const ushort4*)&b2l[(long)(ks+kr)*ldb + sc];
      B2s[kr][sc+0] = h2f(h4.x) + h2f(l4.x);
      B2s[kr][sc+1] = h2f(h4.y) + h2f(l4.y);
      B2s[kr][sc+2] = h2f(h4.z) + h2f(l4.z);
      B2s[kr][sc+3] = h2f(h4.w) + h2f(l4.w);
    }
    __syncthreads();
    #pragma unroll 4
    for (int k = 0; k < 64; ++k){
      f32x4 a4 = *(const f32x4*)&As[k][tm*4];
      f32x4 b4 = *(const f32x4*)&B1s[k][tn*4];
      f32x4 c4 = *(const f32x4*)&B2s[k][tn*4];
      #pragma unroll
      for (int i = 0; i < 4; ++i)
        #pragma unroll
        for (int j = 0; j < 4; ++j){
          acc1[i][j] += a4[i] * b4[j];
          acc2[i][j] += a4[i] * c4[j];
        }
    }
  }
  const long po = ((long)(kc*nbatch + batch) << 12);
  #pragma unroll
  for (int i = 0; i < 4; ++i){
    f32x4 v1 = { acc1[i][0], acc1[i][1], acc1[i][2], acc1[i][3] };
    f32x4 v2 = { acc2[i][0], acc2[i][1], acc2[i][2], acc2[i][3] };
    *(f32x4*)&P1[po + (tm*4+i)*64 + tn*4] = v1;
    *(f32x4*)&P2[po + (tm*4+i)*64 + tn*4] = v2;
  }
}

// ---------------- sum split-K partials -> split f16 planes ----------------
__global__ __launch_bounds__(256)
void reduce64(const float* __restrict__ part,
              u16* __restrict__ outhi, u16* __restrict__ outlo,
              int n4, int parts)
{
  const int idx = blockIdx.x*256 + threadIdx.x;
  if (idx >= n4) return;
  f32x4 s = ((const f32x4*)part)[idx];
  for (int p = 1; p < parts; ++p) s += ((const f32x4*)part)[(long)p*n4 + idx];
  ushort4 uh, ul;
  split1h(s[0], uh.x, ul.x); split1h(s[1], uh.y, ul.y);
  split1h(s[2], uh.z, ul.z); split1h(s[3], uh.w, ul.w);
  ((ushort4*)outhi)[idx] = uh;
  ((ushort4*)outlo)[idx] = ul;
}

// ---------------- stage 2, MFMA: S=qs@gk^T -> softmax(G=64) -> l_attn; O=P@gv -> attn hi ----
__global__ __launch_bounds__(256)
void stage2_mfma(const u16* __restrict__ qhi, const u16* __restrict__ qlo,
                 const u16* __restrict__ gkh_g, const u16* __restrict__ gkl_g,
                 const u16* __restrict__ gvh_g, const u16* __restrict__ gvl_g,
                 float* __restrict__ lattn, u16* __restrict__ ahi,
                 float scale)
{
  __shared__ __align__(16) u16 Ah[128][72];
  __shared__ __align__(16) u16 Al[128][72];
  __shared__ __align__(16) u16 Bh[64][72];
  __shared__ __align__(16) u16 Bl[64][72];
  const int tid = threadIdx.x;
  const int bh = blockIdx.y;
  const int b = bh >> 4, h = bh & 15;
  const int l0 = blockIdx.x * 128;
  const int wm = tid >> 6, lane = tid & 63;

  const long qbase = ((long)b*2048 + l0)*1024 + h*64;
  #pragma unroll
  for (int it = 0; it < 4; ++it){
    const int e = it*256 + tid, row = e >> 3, s = e & 7;
    const long g = qbase + (long)row*1024 + s*8;
    *(uint4*)&Ah[row][s*8] = *(const uint4*)(qhi + g);
    *(uint4*)&Al[row][s*8] = *(const uint4*)(qlo + g);
  }
  const long gb = (long)bh * 4096;
  #pragma unroll
  for (int it = 0; it < 2; ++it){
    const int e = it*256 + tid, gr = e >> 3, s = e & 7;
    *(uint4*)&Bh[gr][s*8] = *(const uint4*)(gkh_g + gb + gr*64 + s*8);
    *(uint4*)&Bl[gr][s*8] = *(const uint4*)(gkl_g + gb + gr*64 + s*8);
  }
  __syncthreads();

  f32x4 acc[2][4] = {};
  #pragma unroll
  for (int k0 = 0; k0 < 64; k0 += 32){
    f16x8 a_h[2], a_l[2], b_h[4], b_l[4];
    #pragma unroll
    for (int mi = 0; mi < 2; ++mi){
      const int row = wm*32 + mi*16 + (lane & 15);
      a_h[mi] = *(const f16x8*)&Ah[row][k0 + (lane >> 4)*8];
      a_l[mi] = *(const f16x8*)&Al[row][k0 + (lane >> 4)*8];
    }
    #pragma unroll
    for (int ni = 0; ni < 4; ++ni){
      const int nr = ni*16 + (lane & 15);
      b_h[ni] = *(const f16x8*)&Bh[nr][k0 + (lane >> 4)*8];
      b_l[ni] = *(const f16x8*)&Bl[nr][k0 + (lane >> 4)*8];
    }
    #pragma unroll
    for (int mi = 0; mi < 2; ++mi)
      #pragma unroll
      for (int ni = 0; ni < 4; ++ni){
        acc[mi][ni] = __builtin_amdgcn_mfma_f32_16x16x32_f16(a_h[mi], b_h[ni], acc[mi][ni], 0, 0, 0);
        acc[mi][ni] = __builtin_amdgcn_mfma_f32_16x16x32_f16(a_l[mi], b_h[ni], acc[mi][ni], 0, 0, 0);
        acc[mi][ni] = __builtin_amdgcn_mfma_f32_16x16x32_f16(a_h[mi], b_l[ni], acc[mi][ni], 0, 0, 0);
      }
  }
  __syncthreads();

  #pragma unroll
  for (int it = 0; it < 4; ++it){
    const int e = it*256 + tid;
    const int gr = e >> 4, d0 = (e & 15) * 4;
    ushort4 vh = *(const ushort4*)(gvh_g + gb + gr*64 + d0);
    ushort4 vl = *(const ushort4*)(gvl_g + gb + gr*64 + d0);
    Bh[d0+0][gr] = vh.x; Bh[d0+1][gr] = vh.y; Bh[d0+2][gr] = vh.z; Bh[d0+3][gr] = vh.w;
    Bl[d0+0][gr] = vl.x; Bl[d0+1][gr] = vl.y; Bl[d0+2][gr] = vl.z; Bl[d0+3][gr] = vl.w;
  }

  #pragma unroll
  for (int mi = 0; mi < 2; ++mi){
    #pragma unroll
    for (int r = 0; r < 4; ++r){
      float v0 = acc[mi][0][r]*scale, v1 = acc[mi][1][r]*scale;
      float v2 = acc[mi][2][r]*scale, v3 = acc[mi][3][r]*scale;
      float mx = fmaxf(fmaxf(v0,v1), fmaxf(v2,v3));
      #pragma unroll
      for (int off = 1; off < 16; off <<= 1) mx = fmaxf(mx, __shfl_xor(mx, off, 16));
      float e0 = __expf(v0-mx), e1 = __expf(v1-mx), e2 = __expf(v2-mx), e3 = __expf(v3-mx);
      float sum = (e0+e1) + (e2+e3);
      #pragma unroll
      for (int off = 1; off < 16; off <<= 1) sum += __shfl_xor(sum, off, 16);
      const float inv = 1.0f / sum;
      e0 *= inv; e1 *= inv; e2 *= inv; e3 *= inv;
      const int lrow = wm*32 + mi*16 + (lane >> 4)*4 + r;
      float* lp = lattn + ((long)bh*2048 + l0 + lrow)*64 + (lane & 15);
      lp[0] = e0; lp[16] = e1; lp[32] = e2; lp[48] = e3;
      u16 hh, ll;
      split1h(e0, hh, ll); Ah[lrow][ 0 + (lane&15)] = hh; Al[lrow][ 0 + (lane&15)] = ll;
      split1h(e1, hh, ll); Ah[lrow][16 + (lane&15)] = hh; Al[lrow][16 + (lane&15)] = ll;
      split1h(e2, hh, ll); Ah[lrow][32 + (lane&15)] = hh; Al[lrow][32 + (lane&15)] = ll;
      split1h(e3, hh, ll); Ah[lrow][48 + (lane&15)] = hh; Al[lrow][48 + (lane&15)] = ll;
    }
  }
  __syncthreads();

  f32x4 o[2][4] = {};
  #pragma unroll
  for (int k0 = 0; k0 < 64; k0 += 32){
    f16x8 p_h[2], p_l[2], b_h[4], b_l[4];
    #pragma unroll
    for (int mi = 0; mi < 2; ++mi){
      const int row = wm*32 + mi*16 + (lane & 15);
      p_h[mi] = *(const f16x8*)&Ah[row][k0 + (lane >> 4)*8];
      p_l[mi] = *(const f16x8*)&Al[row][k0 + (lane >> 4)*8];
    }
    #pragma unroll
    for (int ni = 0; ni < 4; ++ni){
      const int nr = ni*16 + (lane & 15);
      b_h[ni] = *(const f16x8*)&Bh[nr][k0 + (lane >> 4)*8];
      b_l[ni] = *(const f16x8*)&Bl[nr][k0 + (lane >> 4)*8];
    }
    #pragma unroll
    for (int mi = 0; mi < 2; ++mi)
      #pragma unroll
      for (int ni = 0; ni < 4; ++ni){
        o[mi][ni] = __builtin_amdgcn_mfma_f32_16x16x32_f16(p_h[mi], b_h[ni], o[mi][ni], 0, 0, 0);
        o[mi][ni] = __builtin_amdgcn_mfma_f32_16x16x32_f16(p_l[mi], b_h[ni], o[mi][ni], 0, 0, 0);
        o[mi][ni] = __builtin_amdgcn_mfma_f32_16x16x32_f16(p_h[mi], b_l[ni], o[mi][ni], 0, 0, 0);
      }
  }

  #pragma unroll
  for (int mi = 0; mi < 2; ++mi)
    #pragma unroll
    for (int ni = 0; ni < 4; ++ni)
      #pragma unroll
      for (int r = 0; r < 4; ++r){
        const int lrow = wm*32 + mi*16 + (lane >> 4)*4 + r;
        const int d = ni*16 + (lane & 15);
        const long oidx = ((long)b*2048 + l0 + lrow)*1024 + h*64 + d;
        ahi[oidx] = f2h(o[mi][ni][r]);
      }
}

extern "C" void kernel_launch(void* const* d_in, const int* in_sizes, int n_in,
                              void* d_out, int out_size, void* d_ws, size_t ws_size,
                              hipStream_t stream)
{
  const float* query = (const float*)d_in[0];
  const float* key   = (const float*)d_in[1];
  const float* value = (const float*)d_in[2];
  const unsigned char* mask_raw = (const unsigned char*)d_in[4];
  const float* Wq = (const float*)d_in[6];
  const float* Wk = (const float*)d_in[7];
  const float* Wv = (const float*)d_in[8];
  const float* Wi = (const float*)d_in[9];
  const float* Wo = (const float*)d_in[10];
  float* out0 = (float*)d_out;                  // (B,L,E)
  float* out1 = out0 + 16777216;                // (B,H,L,G)

  // ---- workspace: W[0,20) | R1[20,84) | R2 qs[84,148) | R3 vs[148,212) | R4[212,276) MiB ----
  char* ws = (char*)d_ws;
  u16* WoT_hi = (u16*)(ws + 0);
  u16* WqT_hi = (u16*)(ws + (4L<<20));
  u16* WkT_hi = (u16*)(ws + (8L<<20));
  u16* WvT_hi = (u16*)(ws + (12L<<20));
  u16* WiT_hi = (u16*)(ws + (16L<<20));
  // R1: qp -> kp -> vp -> g_scores/g_attn (time-shared)
  u16* qp_hi = (u16*)(ws + (20L<<20));
  u16* kp_hi = qp_hi;
  u16* vp_hi = qp_hi;
  float* gsc  = (float*)(ws + (20L<<20));       // g_scores/g_attn fp32 (64 MiB)
  // R2: qs planes
  u16* qs_hi  = (u16*)(ws + (84L<<20));
  u16* qs_lo  = (u16*)(ws + (116L<<20));
  // R3: vs planes
  u16* vs_hi  = (u16*)(ws + (148L<<20));
  u16* vs_lo  = (u16*)(ws + (180L<<20));
  // R4: ips-scores/wts -> kk planes -> attn plane
  float* ips  = (float*)(ws + (212L<<20));
  u16* kk_hi  = (u16*)(ws + (212L<<20));
  u16* kk_lo  = (u16*)(ws + (244L<<20));
  u16* attn_hi = kk_hi;
  // small overlays on dead W regions:
  float* part1 = (float*)(ws + (4L<<20));       // WqT region, dead after qs-proj
  float* part2 = (float*)(ws + (12L<<20));      // WvT region, dead after vs-proj
  u16* gk_hi = (u16*)(ws + (10L<<20));          // WkT_lo slot (unused)
  u16* gk_lo = (u16*)(ws + (11L<<20));
  u16* gv_hi = (u16*)(ws + (14L<<20));          // WvT_lo slot; written after vs-proj... (part2 uses [12,16)!)
  u16* gv_lo = (u16*)(ws + (15L<<20));
  unsigned char* mask_ws = (unsigned char*)(ws + (18L<<20)); // WiT_lo slot (unused)
  u16* gqs_hi = (u16*)(ws + (17L<<20));         // WiT region tail, dead after ips
  u16* gqs_lo = (u16*)(ws + (19L<<20));
  // NOTE: gv planes at [14,16) overlap part2's tail [12,16). part2 holds 2 KC
  // partials of 128*4096 f32 = 4 MiB at [12,16) -> conflict! Move gv to [2,4)
  // (WoT_lo slot, unused; WoT_hi is [0,2)).
  gv_hi = (u16*)(ws + (2L<<20));
  gv_lo = (u16*)(ws + (3L<<20));

  const dim3 blk(256);
  const float scale = 0.125f;   // 1/sqrt(64)

  // 1) weight transposes -> f16 hi planes
  transpose_hi<<<dim3(16,16), blk, 0, stream>>>(Wq, WqT_hi, 1024, 1024);
  transpose_hi<<<dim3(16,16), blk, 0, stream>>>(Wk, WkT_hi, 1024, 1024);
  transpose_hi<<<dim3(16,16), blk, 0, stream>>>(Wv, WvT_hi, 1024, 1024);
  transpose_hi<<<dim3(16,16), blk, 0, stream>>>(Wi, WiT_hi, 1024, 1024);
  transpose_hi<<<dim3(16,16), blk, 0, stream>>>(Wo, WoT_hi, 1024, 1024);

  // 2) query -> hi plane (R1)
  conv_hi<<<8192, blk, 0, stream>>>(query, qp_hi, 2097152);

  // 3) qs-proj (1-term, swizzled): -> qs hi+lo planes (R2)
  gemm_g<128,1,1,0,1><<<dim3(8,128,1), blk, 0, stream>>>(
      qp_hi, nullptr, WqT_hi, qs_hi, qs_lo, nullptr,
      1024, 1024,1024,1024, 0,0, 0,0, 0,0, 1, 2048, 1.f);

  // 4) ips (1-term): A=WiT_hi, B=qp_hi -> fp32 (R4); then mask + softmax
  gemm_g<128,1,0,0,0><<<dim3(16,8,8), blk, 0, stream>>>(
      WiT_hi, nullptr, qp_hi, ips, nullptr, nullptr,
      1024, 1024,1024,2048, 0,0, 2097152L,0, 2097152L,0, 1, 2048, 1.f);
  mask_norm<<<1, blk, 0, stream>>>(mask_raw, mask_ws, 16384);
  softmax_inplace<<<8192, blk, 0, stream>>>(ips, 2048);

  // 5) gqs[bh] = wts[bh](64xL) @ qs[bh](Lx64) -> planes (part1 on dead WqT)
  einsum64<<<dim3(2,128), blk, 0, stream>>>(ips, qs_hi, qs_lo, part1,
      2048, 2, 2048, 1024, 2097152L, 131072L, 2097152L, 64L, 16, 128);
  reduce64<<<512, blk, 0, stream>>>(part1, gqs_hi, gqs_lo, 131072, 2);

  // 6) key -> hi plane (R1); kk-proj -> kk planes (R4, ips dead)
  conv_hi<<<8192, blk, 0, stream>>>(key, kp_hi, 2097152);
  gemm_g<128,1,1,0,1><<<dim3(8,128,1), blk, 0, stream>>>(
      kp_hi, nullptr, WkT_hi, kk_hi, kk_lo, nullptr,
      1024, 1024,1024,1024, 0,0, 0,0, 0,0, 1, 2048, 1.f);

  // 7) value -> hi plane (R1, kp dead); vs-proj -> vs planes (R3)
  conv_hi<<<8192, blk, 0, stream>>>(value, vp_hi, 2097152);
  gemm_g<128,1,1,0,1><<<dim3(8,128,1), blk, 0, stream>>>(
      vp_hi, nullptr, WvT_hi, vs_hi, vs_lo, nullptr,
      1024, 1024,1024,1024, 0,0, 0,0, 0,0, 1, 2048, 1.f);

  // 8) g_scores (2-term A = gqs hi+lo): -> gsc fp32 (R1, vp dead); softmax
  gemm_g<64,2,0,1,0><<<dim3(16,1,128), blk, 0, stream>>>(
      gqs_hi, gqs_lo, kk_hi, gsc, nullptr, mask_ws,
      64, 64,1024,2048, 65536L,4096L, 2097152L,64L, 2097152L,131072L, 16, 2048, scale);
  softmax_inplace<<<8192, blk, 0, stream>>>(gsc, 2048);

  // 9) gk/gv[bh] = g_attn @ {kk,vs} -> planes
  einsum64_dual<<<dim3(2,128), blk, 0, stream>>>(gsc, kk_hi, kk_lo, vs_hi, vs_lo,
      part1, part2, 2048, 2, 2048, 1024, 2097152L, 131072L, 2097152L, 64L, 16, 128);
  reduce64<<<512, blk, 0, stream>>>(part1, gk_hi, gk_lo, 131072, 2);
  reduce64<<<512, blk, 0, stream>>>(part2, gv_hi, gv_lo, 131072, 2);

  // 10) stage 2 (MFMA): l_attn (out1) + attn hi plane (R4, kk dead)
  stage2_mfma<<<dim3(16,128), blk, 0, stream>>>(qs_hi, qs_lo, gk_hi, gk_lo,
      gv_hi, gv_lo, out1, attn_hi, scale);

  // 11) out0 = attn @ Wo (1-term, swizzled)
  gemm_g<128,1,0,0,1><<<dim3(8,128,1), blk, 0, stream>>>(
      attn_hi, nullptr, WoT_hi, out0, nullptr, nullptr,
      1024, 1024,1024,1024, 0,0, 0,0, 0,0, 1, 2048, 1.f);

  (void)in_sizes; (void)n_in; (void)out_size; (void)ws_size;
}

// Round 8
// 576.472 us; speedup vs baseline: 1.5378x; 1.0833x over previous
//
#include <hip/hip_runtime.h>

// EGA multi-headed attention, MI355X/gfx950.
// Round 8: einsums -> 3-term f16 MFMA (split-K=4); softmaxes operate on f16
//          hi/lo planes in place; ips/g_scores GEMMs emit planes (mask=-5e4).
// Dims fixed: B=8, L=S=2048, E=1024, H=16, G=64, Ek=Ev=64, KD=VD=1024.

typedef float f32x4 __attribute__((ext_vector_type(4)));
typedef _Float16 f16x8 __attribute__((ext_vector_type(8)));
typedef unsigned short u16;

#define DEV static __device__ __forceinline__

DEV u16 f2h(float x){
  _Float16 h = (_Float16)x;
  return __builtin_bit_cast(u16, h);
}
DEV float h2f(u16 u){
  return (float)__builtin_bit_cast(_Float16, u);
}
DEV void split1h(float x, u16 &h, u16 &l){
  h = f2h(x);
  l = f2h(x - h2f(h));
}
DEV unsigned pk2h(float a, float b){
  return (unsigned)f2h(a) | ((unsigned)f2h(b) << 16);
}

// async global->LDS, 16B per lane; dst is wave-uniform base (HW adds lane*16)
DEV void gload16(const u16* src, u16* dst_lds){
  __builtin_amdgcn_global_load_lds(
      (__attribute__((address_space(1))) void*)src,
      (__attribute__((address_space(3))) void*)dst_lds, 16, 0, 0);
}

// ---------------- mask dtype sniff + normalize to uchar ----------------
__global__ __launch_bounds__(256)
void mask_norm(const unsigned char* __restrict__ src, unsigned char* __restrict__ dst, int n)
{
  const unsigned* w = (const unsigned*)src;
  const int tid = threadIdx.x;
  int local = 0;
  for (int i = tid; i < n/4; i += 256){
    unsigned v = w[i];
    if (v == 0x3F800000u) local |= 2;
    else if (v > 1u)      local |= 1;
  }
  __shared__ int red[256];
  red[tid] = local;
  __syncthreads();
  for (int s = 128; s; s >>= 1){
    if (tid < s) red[tid] |= red[tid+s];
    __syncthreads();
  }
  const int r = red[0];
  const int mode = (r & 2) ? 2 : ((r & 1) ? 1 : 0);   // 2=f32, 1=u8, 0=i32
  for (int i = tid; i < n; i += 256){
    unsigned char v;
    if (mode == 1) v = src[i] ? 1 : 0;
    else           v = w[i]   ? 1 : 0;
    dst[i] = v;
  }
}

// ---------------- fp32 -> f16 hi plane only (8 elems/thread) ----------------
__global__ __launch_bounds__(256)
void conv_hi(const float* __restrict__ x, u16* __restrict__ hi, int n8)
{
  const int i = blockIdx.x*256 + threadIdx.x;
  if (i >= n8) return;
  f32x4 a = ((const f32x4*)x)[2*i], b = ((const f32x4*)x)[2*i+1];
  uint4 uh;
  uh.x = pk2h(a[0], a[1]); uh.y = pk2h(a[2], a[3]);
  uh.z = pk2h(b[0], b[1]); uh.w = pk2h(b[2], b[3]);
  ((uint4*)hi)[i] = uh;
}

// ---------------- 1024x1024 transpose, fp32 -> f16 hi plane ----------------
__global__ __launch_bounds__(256)
void transpose_hi(const float* __restrict__ Wsrc, u16* __restrict__ Whi, int Kd, int Nd)
{
  __shared__ float t[64][65];
  const int tid = threadIdx.x;
  const int n0 = blockIdx.x * 64, k0 = blockIdx.y * 64;
  #pragma unroll
  for (int it = 0; it < 16; ++it){
    int e = it*256 + tid, r = e >> 6, c = e & 63;
    t[r][c] = Wsrc[(long)(k0+r)*Nd + (n0+c)];
  }
  __syncthreads();
  #pragma unroll
  for (int it = 0; it < 16; ++it){
    int e = it*256 + tid, r = e >> 6, c = e & 63;
    Whi[(long)(n0+r)*Kd + (k0+c)] = f2h(t[c][r]);
  }
}

// ---------------- f16 MFMA GEMM, global_load_lds staging, dbuf ----------------
// C[m,n] = sum_k A[m,k]*Bt[n,k].  TERMS=1: A=hi; TERMS=2: A=hi+lo. B=hi.
// CM: 0 = fp32 out; 1 = split f16 planes out.  EPI==1: scale+mask(-5e4).
// SWZ: XCD-chunked bijective block swizzle (requires nwg%8==0, gridDim.z==1).
template<int TM, int TERMS, int CM, int EPI, int SWZ>
__global__ __launch_bounds__(256)
void gemm_g(const u16* __restrict__ Ah_g, const u16* __restrict__ Al_g,
            const u16* __restrict__ Bh_g,
            void* __restrict__ Cp, void* __restrict__ Cp2,
            const unsigned char* __restrict__ maskp,
            int K, int lda, int ldb, int ldc,
            long aB, long aH, long bB, long bH, long cB, long cH,
            int H2, int Ssz, float scale)
{
  constexpr int BN = 128, BK = 32;
  constexpr int WM = TM/2, WN = BN/2;
  constexpr int FM = WM/16, FN = WN/16;
  __shared__ __align__(16) u16 AhS[2][TM*BK];
  __shared__ __align__(16) u16 AlS[2][TERMS == 2 ? TM*BK : 8];
  __shared__ __align__(16) u16 BhS[2][BN*BK];

  const int tid = threadIdx.x;
  int bx = blockIdx.x, by = blockIdx.y;
  if constexpr (SWZ){
    const int gx = gridDim.x;
    const int nwg = gx * gridDim.y;
    const int q = nwg >> 3;
    const int flat = bx + gx * by;
    const int nf = (flat & 7) * q + (flat >> 3);
    bx = nf % gx; by = nf / gx;
  }
  const int batch = blockIdx.z;
  const int b = batch / H2, h = batch - b*H2;
  const long aOff = (long)b*aB + (long)h*aH;
  const long bOff = (long)b*bB + (long)h*bH;
  const long cOff = (long)b*cB + (long)h*cH;
  const int nBase = bx * BN;
  const int mBase = by * TM;
  const int wave = tid >> 6, lane = tid & 63;
  const int wm = wave >> 1, wn = wave & 1;
  const int cg8 = (lane & 3) * 8;
  const int rsub = lane >> 2;

  auto stage = [&](int buf, int k0){
    #pragma unroll
    for (int c = 0; c < TM/64; ++c){
      const int chunk = wave*(TM/64) + c;
      const long g = aOff + (long)(mBase + chunk*16 + rsub)*lda + k0 + cg8;
      gload16(Ah_g + g, &AhS[buf][chunk*512]);
      if constexpr (TERMS == 2) gload16(Al_g + g, &AlS[buf][chunk*512]);
    }
    #pragma unroll
    for (int c = 0; c < 2; ++c){
      const int chunk = wave*2 + c;
      const long g = bOff + (long)(nBase + chunk*16 + rsub)*ldb + k0 + cg8;
      gload16(Bh_g + g, &BhS[buf][chunk*512]);
    }
  };

  f32x4 acc[FM][FN] = {};

  stage(0, 0);
  __syncthreads();
  const int nk = K >> 5;
  for (int t = 0; t < nk; ++t){
    const int buf = t & 1;
    if (t + 1 < nk) stage(buf ^ 1, (t + 1) << 5);

    f16x8 ah[FM], al[FM], bh[FN];
    #pragma unroll
    for (int mi = 0; mi < FM; ++mi){
      const int off = (wm*WM + mi*16 + (lane & 15))*BK + (lane >> 4)*8;
      ah[mi] = *(const f16x8*)&AhS[buf][off];
      if constexpr (TERMS == 2) al[mi] = *(const f16x8*)&AlS[buf][off];
    }
    #pragma unroll
    for (int ni = 0; ni < FN; ++ni){
      const int off = (wn*WN + ni*16 + (lane & 15))*BK + (lane >> 4)*8;
      bh[ni] = *(const f16x8*)&BhS[buf][off];
    }
    #pragma unroll
    for (int mi = 0; mi < FM; ++mi)
      #pragma unroll
      for (int ni = 0; ni < FN; ++ni){
        acc[mi][ni] = __builtin_amdgcn_mfma_f32_16x16x32_f16(ah[mi], bh[ni], acc[mi][ni], 0, 0, 0);
        if constexpr (TERMS == 2)
          acc[mi][ni] = __builtin_amdgcn_mfma_f32_16x16x32_f16(al[mi], bh[ni], acc[mi][ni], 0, 0, 0);
      }
    __syncthreads();
  }

  const int cr = (lane >> 4) * 4, cc = lane & 15;
  #pragma unroll
  for (int mi = 0; mi < FM; ++mi)
    #pragma unroll
    for (int ni = 0; ni < FN; ++ni)
      #pragma unroll
      for (int r = 0; r < 4; ++r){
        const int row = mBase + wm*WM + mi*16 + cr + r;
        const int col = nBase + wn*WN + ni*16 + cc;
        float v = acc[mi][ni][r];
        if constexpr (EPI == 1){
          v *= scale;
          if (maskp[(long)b*Ssz + col]) v = -50000.0f;
        }
        const long ci = cOff + (long)row*ldc + col;
        if constexpr (CM == 0){
          ((float*)Cp)[ci] = v;
        } else {
          u16 hh, ll;
          split1h(v, hh, ll);
          ((u16*)Cp)[ci]  = hh;
          ((u16*)Cp2)[ci] = ll;
        }
      }
}

// ---------------- row softmax (width 2048) on f16 hi/lo planes, in place ----------------
__global__ __launch_bounds__(256)
void softmax_split(u16* __restrict__ hi, u16* __restrict__ lo)
{
  const long base = (long)blockIdx.x * 2048;
  const int tid = threadIdx.x;
  const int lane = tid & 63, wv = tid >> 6;
  uint4 uh = ((const uint4*)(hi + base))[tid];
  uint4 ul = ((const uint4*)(lo + base))[tid];
  float v[8];
  v[0] = h2f((u16)uh.x) + h2f((u16)ul.x);
  v[1] = h2f((u16)(uh.x>>16)) + h2f((u16)(ul.x>>16));
  v[2] = h2f((u16)uh.y) + h2f((u16)ul.y);
  v[3] = h2f((u16)(uh.y>>16)) + h2f((u16)(ul.y>>16));
  v[4] = h2f((u16)uh.z) + h2f((u16)ul.z);
  v[5] = h2f((u16)(uh.z>>16)) + h2f((u16)(ul.z>>16));
  v[6] = h2f((u16)uh.w) + h2f((u16)ul.w);
  v[7] = h2f((u16)(uh.w>>16)) + h2f((u16)(ul.w>>16));
  float m = v[0];
  #pragma unroll
  for (int i = 1; i < 8; ++i) m = fmaxf(m, v[i]);
  #pragma unroll
  for (int off = 32; off; off >>= 1) m = fmaxf(m, __shfl_xor(m, off));
  __shared__ float rm[4], rs[4];
  if (lane == 0) rm[wv] = m;
  __syncthreads();
  m = fmaxf(fmaxf(rm[0],rm[1]), fmaxf(rm[2],rm[3]));
  float s = 0.f;
  #pragma unroll
  for (int i = 0; i < 8; ++i){ v[i] = __expf(v[i]-m); s += v[i]; }
  #pragma unroll
  for (int off = 32; off; off >>= 1) s += __shfl_xor(s, off);
  if (lane == 0) rs[wv] = s;
  __syncthreads();
  s = (rs[0]+rs[1]) + (rs[2]+rs[3]);
  const float inv = 1.0f / s;
  u16 hh[8], ll[8];
  #pragma unroll
  for (int i = 0; i < 8; ++i) split1h(v[i]*inv, hh[i], ll[i]);
  uh.x = (unsigned)hh[0] | ((unsigned)hh[1]<<16);
  uh.y = (unsigned)hh[2] | ((unsigned)hh[3]<<16);
  uh.z = (unsigned)hh[4] | ((unsigned)hh[5]<<16);
  uh.w = (unsigned)hh[6] | ((unsigned)hh[7]<<16);
  ul.x = (unsigned)ll[0] | ((unsigned)ll[1]<<16);
  ul.y = (unsigned)ll[2] | ((unsigned)ll[3]<<16);
  ul.z = (unsigned)ll[4] | ((unsigned)ll[5]<<16);
  ul.w = (unsigned)ll[6] | ((unsigned)ll[7]<<16);
  ((uint4*)(hi + base))[tid] = uh;
  ((uint4*)(lo + base))[tid] = ul;
}

// ---------------- MFMA einsum: C[g][d] = sum_l A[g][l]*B[l][d], 3-term f16 ----------------
// A planes (g,l) k-contig; B planes (l,d) transpose-staged to LDS [d][l].
// NB=2: second B tensor shares A (gk/gv dual). Partials per (kc,batch).
template<int NB>
__global__ __launch_bounds__(256)
void einsum_m(const u16* __restrict__ Ah_g, const u16* __restrict__ Al_g,
              const u16* __restrict__ B1h_g, const u16* __restrict__ B1l_g,
              const u16* __restrict__ B2h_g, const u16* __restrict__ B2l_g,
              float* __restrict__ P1, float* __restrict__ P2,
              int K, int KC, int lda, int ldb,
              long aB, long aH, long bB, long bH, int H2, int nbatch)
{
  __shared__ __align__(16) u16 AhS[64][72];
  __shared__ __align__(16) u16 AlS[64][72];
  __shared__ __align__(16) u16 B1hS[64][72];
  __shared__ __align__(16) u16 B1lS[64][72];
  __shared__ __align__(16) u16 B2hS[NB==2?64:1][72];
  __shared__ __align__(16) u16 B2lS[NB==2?64:1][72];
  const int tid = threadIdx.x;
  const int kc = blockIdx.x, batch = blockIdx.y;
  const int b = batch / H2, h = batch - b*H2;
  const long aOff = (long)b*aB + (long)h*aH;
  const long bOff = (long)b*bB + (long)h*bH;
  const int kchunk = K / KC, kbeg = kc * kchunk;
  const int wm = tid >> 6, lane = tid & 63;
  const int ar = tid >> 3, as = (tid & 7) * 8;

  f32x4 acc1[4] = {};
  f32x4 acc2[4] = {};

  for (int ks = kbeg; ks < kbeg + kchunk; ks += 64){
    if (ks != kbeg) __syncthreads();
    // A stage (copy): rows g, cols l
    #pragma unroll
    for (int it = 0; it < 2; ++it){
      const int g = it*32 + ar;
      const long ga = aOff + (long)g*lda + ks + as;
      *(uint4*)&AhS[g][as] = *(const uint4*)(Ah_g + ga);
      *(uint4*)&AlS[g][as] = *(const uint4*)(Al_g + ga);
    }
    // B stage (transpose): read (l,d) rows, write [d][l]
    #pragma unroll
    for (int it = 0; it < 4; ++it){
      const int e = it*256 + tid;
      const int lr = e >> 4, d0 = (e & 15) * 4;
      const long gm = bOff + (long)(ks + lr)*ldb + d0;
      ushort4 h4 = *(const ushort4*)(B1h_g + gm);
      ushort4 l4 = *(const ushort4*)(B1l_g + gm);
      B1hS[d0+0][lr]=h4.x; B1hS[d0+1][lr]=h4.y; B1hS[d0+2][lr]=h4.z; B1hS[d0+3][lr]=h4.w;
      B1lS[d0+0][lr]=l4.x; B1lS[d0+1][lr]=l4.y; B1lS[d0+2][lr]=l4.z; B1lS[d0+3][lr]=l4.w;
      if constexpr (NB == 2){
        ushort4 h42 = *(const ushort4*)(B2h_g + gm);
        ushort4 l42 = *(const ushort4*)(B2l_g + gm);
        B2hS[d0+0][lr]=h42.x; B2hS[d0+1][lr]=h42.y; B2hS[d0+2][lr]=h42.z; B2hS[d0+3][lr]=h42.w;
        B2lS[d0+0][lr]=l42.x; B2lS[d0+1][lr]=l42.y; B2lS[d0+2][lr]=l42.z; B2lS[d0+3][lr]=l42.w;
      }
    }
    __syncthreads();
    #pragma unroll
    for (int k0 = 0; k0 < 64; k0 += 32){
      const int ko = k0 + (lane >> 4)*8;
      const int fr = lane & 15;
      f16x8 a_h = *(const f16x8*)&AhS[wm*16 + fr][ko];
      f16x8 a_l = *(const f16x8*)&AlS[wm*16 + fr][ko];
      #pragma unroll
      for (int ni = 0; ni < 4; ++ni){
        f16x8 b_h = *(const f16x8*)&B1hS[ni*16 + fr][ko];
        f16x8 b_l = *(const f16x8*)&B1lS[ni*16 + fr][ko];
        acc1[ni] = __builtin_amdgcn_mfma_f32_16x16x32_f16(a_h, b_h, acc1[ni], 0, 0, 0);
        acc1[ni] = __builtin_amdgcn_mfma_f32_16x16x32_f16(a_l, b_h, acc1[ni], 0, 0, 0);
        acc1[ni] = __builtin_amdgcn_mfma_f32_16x16x32_f16(a_h, b_l, acc1[ni], 0, 0, 0);
        if constexpr (NB == 2){
          f16x8 c_h = *(const f16x8*)&B2hS[ni*16 + fr][ko];
          f16x8 c_l = *(const f16x8*)&B2lS[ni*16 + fr][ko];
          acc2[ni] = __builtin_amdgcn_mfma_f32_16x16x32_f16(a_h, c_h, acc2[ni], 0, 0, 0);
          acc2[ni] = __builtin_amdgcn_mfma_f32_16x16x32_f16(a_l, c_h, acc2[ni], 0, 0, 0);
          acc2[ni] = __builtin_amdgcn_mfma_f32_16x16x32_f16(a_h, c_l, acc2[ni], 0, 0, 0);
        }
      }
    }
  }
  const long po = ((long)(kc*nbatch + batch) << 12);
  const int cr = (lane >> 4) * 4, cc = lane & 15;
  #pragma unroll
  for (int ni = 0; ni < 4; ++ni)
    #pragma unroll
    for (int r = 0; r < 4; ++r){
      const int g = wm*16 + cr + r, d = ni*16 + cc;
      P1[po + g*64 + d] = acc1[ni][r];
      if constexpr (NB == 2) P2[po + g*64 + d] = acc2[ni][r];
    }
}

// ---------------- sum split-K partials -> split f16 planes ----------------
__global__ __launch_bounds__(256)
void reduce64(const float* __restrict__ part,
              u16* __restrict__ outhi, u16* __restrict__ outlo,
              int n4, int parts)
{
  const int idx = blockIdx.x*256 + threadIdx.x;
  if (idx >= n4) return;
  f32x4 s = ((const f32x4*)part)[idx];
  for (int p = 1; p < parts; ++p) s += ((const f32x4*)part)[(long)p*n4 + idx];
  ushort4 uh, ul;
  split1h(s[0], uh.x, ul.x); split1h(s[1], uh.y, ul.y);
  split1h(s[2], uh.z, ul.z); split1h(s[3], uh.w, ul.w);
  ((ushort4*)outhi)[idx] = uh;
  ((ushort4*)outlo)[idx] = ul;
}

// ---------------- stage 2, MFMA: S=qs@gk^T -> softmax(G=64) -> l_attn; O=P@gv -> attn hi ----
__global__ __launch_bounds__(256)
void stage2_mfma(const u16* __restrict__ qhi, const u16* __restrict__ qlo,
                 const u16* __restrict__ gkh_g, const u16* __restrict__ gkl_g,
                 const u16* __restrict__ gvh_g, const u16* __restrict__ gvl_g,
                 float* __restrict__ lattn, u16* __restrict__ ahi,
                 float scale)
{
  __shared__ __align__(16) u16 Ah[128][72];
  __shared__ __align__(16) u16 Al[128][72];
  __shared__ __align__(16) u16 Bh[64][72];
  __shared__ __align__(16) u16 Bl[64][72];
  const int tid = threadIdx.x;
  const int bh = blockIdx.y;
  const int b = bh >> 4, h = bh & 15;
  const int l0 = blockIdx.x * 128;
  const int wm = tid >> 6, lane = tid & 63;

  const long qbase = ((long)b*2048 + l0)*1024 + h*64;
  #pragma unroll
  for (int it = 0; it < 4; ++it){
    const int e = it*256 + tid, row = e >> 3, s = e & 7;
    const long g = qbase + (long)row*1024 + s*8;
    *(uint4*)&Ah[row][s*8] = *(const uint4*)(qhi + g);
    *(uint4*)&Al[row][s*8] = *(const uint4*)(qlo + g);
  }
  const long gb = (long)bh * 4096;
  #pragma unroll
  for (int it = 0; it < 2; ++it){
    const int e = it*256 + tid, gr = e >> 3, s = e & 7;
    *(uint4*)&Bh[gr][s*8] = *(const uint4*)(gkh_g + gb + gr*64 + s*8);
    *(uint4*)&Bl[gr][s*8] = *(const uint4*)(gkl_g + gb + gr*64 + s*8);
  }
  __syncthreads();

  f32x4 acc[2][4] = {};
  #pragma unroll
  for (int k0 = 0; k0 < 64; k0 += 32){
    f16x8 a_h[2], a_l[2], b_h[4], b_l[4];
    #pragma unroll
    for (int mi = 0; mi < 2; ++mi){
      const int row = wm*32 + mi*16 + (lane & 15);
      a_h[mi] = *(const f16x8*)&Ah[row][k0 + (lane >> 4)*8];
      a_l[mi] = *(const f16x8*)&Al[row][k0 + (lane >> 4)*8];
    }
    #pragma unroll
    for (int ni = 0; ni < 4; ++ni){
      const int nr = ni*16 + (lane & 15);
      b_h[ni] = *(const f16x8*)&Bh[nr][k0 + (lane >> 4)*8];
      b_l[ni] = *(const f16x8*)&Bl[nr][k0 + (lane >> 4)*8];
    }
    #pragma unroll
    for (int mi = 0; mi < 2; ++mi)
      #pragma unroll
      for (int ni = 0; ni < 4; ++ni){
        acc[mi][ni] = __builtin_amdgcn_mfma_f32_16x16x32_f16(a_h[mi], b_h[ni], acc[mi][ni], 0, 0, 0);
        acc[mi][ni] = __builtin_amdgcn_mfma_f32_16x16x32_f16(a_l[mi], b_h[ni], acc[mi][ni], 0, 0, 0);
        acc[mi][ni] = __builtin_amdgcn_mfma_f32_16x16x32_f16(a_h[mi], b_l[ni], acc[mi][ni], 0, 0, 0);
      }
  }
  __syncthreads();

  #pragma unroll
  for (int it = 0; it < 4; ++it){
    const int e = it*256 + tid;
    const int gr = e >> 4, d0 = (e & 15) * 4;
    ushort4 vh = *(const ushort4*)(gvh_g + gb + gr*64 + d0);
    ushort4 vl = *(const ushort4*)(gvl_g + gb + gr*64 + d0);
    Bh[d0+0][gr] = vh.x; Bh[d0+1][gr] = vh.y; Bh[d0+2][gr] = vh.z; Bh[d0+3][gr] = vh.w;
    Bl[d0+0][gr] = vl.x; Bl[d0+1][gr] = vl.y; Bl[d0+2][gr] = vl.z; Bl[d0+3][gr] = vl.w;
  }

  #pragma unroll
  for (int mi = 0; mi < 2; ++mi){
    #pragma unroll
    for (int r = 0; r < 4; ++r){
      float v0 = acc[mi][0][r]*scale, v1 = acc[mi][1][r]*scale;
      float v2 = acc[mi][2][r]*scale, v3 = acc[mi][3][r]*scale;
      float mx = fmaxf(fmaxf(v0,v1), fmaxf(v2,v3));
      #pragma unroll
      for (int off = 1; off < 16; off <<= 1) mx = fmaxf(mx, __shfl_xor(mx, off, 16));
      float e0 = __expf(v0-mx), e1 = __expf(v1-mx), e2 = __expf(v2-mx), e3 = __expf(v3-mx);
      float sum = (e0+e1) + (e2+e3);
      #pragma unroll
      for (int off = 1; off < 16; off <<= 1) sum += __shfl_xor(sum, off, 16);
      const float inv = 1.0f / sum;
      e0 *= inv; e1 *= inv; e2 *= inv; e3 *= inv;
      const int lrow = wm*32 + mi*16 + (lane >> 4)*4 + r;
      float* lp = lattn + ((long)bh*2048 + l0 + lrow)*64 + (lane & 15);
      lp[0] = e0; lp[16] = e1; lp[32] = e2; lp[48] = e3;
      u16 hh, ll;
      split1h(e0, hh, ll); Ah[lrow][ 0 + (lane&15)] = hh; Al[lrow][ 0 + (lane&15)] = ll;
      split1h(e1, hh, ll); Ah[lrow][16 + (lane&15)] = hh; Al[lrow][16 + (lane&15)] = ll;
      split1h(e2, hh, ll); Ah[lrow][32 + (lane&15)] = hh; Al[lrow][32 + (lane&15)] = ll;
      split1h(e3, hh, ll); Ah[lrow][48 + (lane&15)] = hh; Al[lrow][48 + (lane&15)] = ll;
    }
  }
  __syncthreads();

  f32x4 o[2][4] = {};
  #pragma unroll
  for (int k0 = 0; k0 < 64; k0 += 32){
    f16x8 p_h[2], p_l[2], b_h[4], b_l[4];
    #pragma unroll
    for (int mi = 0; mi < 2; ++mi){
      const int row = wm*32 + mi*16 + (lane & 15);
      p_h[mi] = *(const f16x8*)&Ah[row][k0 + (lane >> 4)*8];
      p_l[mi] = *(const f16x8*)&Al[row][k0 + (lane >> 4)*8];
    }
    #pragma unroll
    for (int ni = 0; ni < 4; ++ni){
      const int nr = ni*16 + (lane & 15);
      b_h[ni] = *(const f16x8*)&Bh[nr][k0 + (lane >> 4)*8];
      b_l[ni] = *(const f16x8*)&Bl[nr][k0 + (lane >> 4)*8];
    }
    #pragma unroll
    for (int mi = 0; mi < 2; ++mi)
      #pragma unroll
      for (int ni = 0; ni < 4; ++ni){
        o[mi][ni] = __builtin_amdgcn_mfma_f32_16x16x32_f16(p_h[mi], b_h[ni], o[mi][ni], 0, 0, 0);
        o[mi][ni] = __builtin_amdgcn_mfma_f32_16x16x32_f16(p_l[mi], b_h[ni], o[mi][ni], 0, 0, 0);
        o[mi][ni] = __builtin_amdgcn_mfma_f32_16x16x32_f16(p_h[mi], b_l[ni], o[mi][ni], 0, 0, 0);
      }
  }

  #pragma unroll
  for (int mi = 0; mi < 2; ++mi)
    #pragma unroll
    for (int ni = 0; ni < 4; ++ni)
      #pragma unroll
      for (int r = 0; r < 4; ++r){
        const int lrow = wm*32 + mi*16 + (lane >> 4)*4 + r;
        const int d = ni*16 + (lane & 15);
        const long oidx = ((long)b*2048 + l0 + lrow)*1024 + h*64 + d;
        ahi[oidx] = f2h(o[mi][ni][r]);
      }
}

extern "C" void kernel_launch(void* const* d_in, const int* in_sizes, int n_in,
                              void* d_out, int out_size, void* d_ws, size_t ws_size,
                              hipStream_t stream)
{
  const float* query = (const float*)d_in[0];
  const float* key   = (const float*)d_in[1];
  const float* value = (const float*)d_in[2];
  const unsigned char* mask_raw = (const unsigned char*)d_in[4];
  const float* Wq = (const float*)d_in[6];
  const float* Wk = (const float*)d_in[7];
  const float* Wv = (const float*)d_in[8];
  const float* Wi = (const float*)d_in[9];
  const float* Wo = (const float*)d_in[10];
  float* out0 = (float*)d_out;                  // (B,L,E)
  float* out1 = out0 + 16777216;                // (B,H,L,G)

  // ---- workspace map (MiB) ----
  // [0,2)   WoT_hi (live to end)
  // [2,4)   free
  // [4,6)   WqT_hi (dead after qs-proj)     } dual part1 [4,12) @step9
  // [6,8)   mask_ws @6 (dead after step8)   }
  // [8,10)  WkT_hi (dead after kk-proj)     }
  // [10,12) free                            }
  // [12,14) WvT_hi (dead after vs-proj)     } dual part2 [12,20) @step9
  // [14,16) free                            }
  // [16,17) gqs_hi, [17,18) gqs_lo (WiT dead after ips; gqs dead after step8)
  // [18,20) WiT_hi... NOTE WiT_hi placed at [18,20)
  // [20,52)  R1: qp/kp/vp hi -> gsc_hi ; [52,84) gsc_lo
  // [84,116) qs_hi ; [116,148) qs_lo
  // [148,156) gqs partials (before vs written) ; [148,180) vs_hi ; [180,212) vs_lo
  // [212,244) ips_hi -> kk_hi -> gk/gv planes @212..216 ; [244,276) ips_lo -> kk_lo -> attn_hi
  char* ws = (char*)d_ws;
  u16* WoT_hi = (u16*)(ws + 0);
  u16* WqT_hi = (u16*)(ws + (4L<<20));
  u16* WkT_hi = (u16*)(ws + (8L<<20));
  u16* WvT_hi = (u16*)(ws + (12L<<20));
  u16* WiT_hi = (u16*)(ws + (18L<<20));
  unsigned char* mask_ws = (unsigned char*)(ws + (6L<<20));
  u16* gqs_hi = (u16*)(ws + (16L<<20));
  u16* gqs_lo = (u16*)(ws + (17L<<20));
  float* part1 = (float*)(ws + (4L<<20));       // 8 MiB, step9
  float* part2 = (float*)(ws + (12L<<20));      // 8 MiB, step9
  // R1
  u16* qp_hi = (u16*)(ws + (20L<<20));
  u16* kp_hi = qp_hi;
  u16* vp_hi = qp_hi;
  u16* gsc_hi = (u16*)(ws + (20L<<20));
  u16* gsc_lo = (u16*)(ws + (52L<<20));
  // R2
  u16* qs_hi  = (u16*)(ws + (84L<<20));
  u16* qs_lo  = (u16*)(ws + (116L<<20));
  // R3
  float* partg = (float*)(ws + (148L<<20));     // 8 MiB, step5 (before vs)
  u16* vs_hi  = (u16*)(ws + (148L<<20));
  u16* vs_lo  = (u16*)(ws + (180L<<20));
  // R4
  u16* ips_hi = (u16*)(ws + (212L<<20));
  u16* ips_lo = (u16*)(ws + (244L<<20));
  u16* kk_hi  = (u16*)(ws + (212L<<20));
  u16* kk_lo  = (u16*)(ws + (244L<<20));
  u16* gk_hi  = (u16*)(ws + (212L<<20));        // over dead kk (after dual)
  u16* gk_lo  = (u16*)(ws + (213L<<20));
  u16* gv_hi  = (u16*)(ws + (214L<<20));
  u16* gv_lo  = (u16*)(ws + (215L<<20));
  u16* attn_hi = (u16*)(ws + (244L<<20));       // over dead kk_lo

  const dim3 blk(256);
  const float scale = 0.125f;   // 1/sqrt(64)

  // 1) weight transposes -> f16 hi planes
  transpose_hi<<<dim3(16,16), blk, 0, stream>>>(Wq, WqT_hi, 1024, 1024);
  transpose_hi<<<dim3(16,16), blk, 0, stream>>>(Wk, WkT_hi, 1024, 1024);
  transpose_hi<<<dim3(16,16), blk, 0, stream>>>(Wv, WvT_hi, 1024, 1024);
  transpose_hi<<<dim3(16,16), blk, 0, stream>>>(Wi, WiT_hi, 1024, 1024);
  transpose_hi<<<dim3(16,16), blk, 0, stream>>>(Wo, WoT_hi, 1024, 1024);

  // 2) query -> hi plane (R1)
  conv_hi<<<8192, blk, 0, stream>>>(query, qp_hi, 2097152);

  // 3) qs-proj (1-term, swizzled) -> qs planes (R2)
  gemm_g<128,1,1,0,1><<<dim3(8,128,1), blk, 0, stream>>>(
      qp_hi, nullptr, WqT_hi, qs_hi, qs_lo, nullptr,
      1024, 1024,1024,1024, 0,0, 0,0, 0,0, 1, 2048, 1.f);

  // 4) ips (1-term) -> f16 planes (R4); softmax over L in place
  gemm_g<128,1,1,0,0><<<dim3(16,8,8), blk, 0, stream>>>(
      WiT_hi, nullptr, qp_hi, ips_hi, ips_lo, nullptr,
      1024, 1024,1024,2048, 0,0, 2097152L,0, 2097152L,0, 1, 2048, 1.f);
  mask_norm<<<1, blk, 0, stream>>>(mask_raw, mask_ws, 16384);
  softmax_split<<<8192, blk, 0, stream>>>(ips_hi, ips_lo);

  // 5) gqs = wts @ qs (MFMA einsum, KC=4; partials in pre-vs R3)
  einsum_m<1><<<dim3(4,128), blk, 0, stream>>>(
      ips_hi, ips_lo, qs_hi, qs_lo, nullptr, nullptr, partg, nullptr,
      2048, 4, 2048, 1024, 2097152L, 131072L, 2097152L, 64L, 16, 128);
  reduce64<<<512, blk, 0, stream>>>(partg, gqs_hi, gqs_lo, 131072, 4);

  // 6) key -> hi plane (R1, qp dead); kk-proj -> kk planes (R4, wts dead)
  conv_hi<<<8192, blk, 0, stream>>>(key, kp_hi, 2097152);
  gemm_g<128,1,1,0,1><<<dim3(8,128,1), blk, 0, stream>>>(
      kp_hi, nullptr, WkT_hi, kk_hi, kk_lo, nullptr,
      1024, 1024,1024,1024, 0,0, 0,0, 0,0, 1, 2048, 1.f);

  // 7) value -> hi plane (R1, kp dead); vs-proj -> vs planes (R3, partg dead)
  conv_hi<<<8192, blk, 0, stream>>>(value, vp_hi, 2097152);
  gemm_g<128,1,1,0,1><<<dim3(8,128,1), blk, 0, stream>>>(
      vp_hi, nullptr, WvT_hi, vs_hi, vs_lo, nullptr,
      1024, 1024,1024,1024, 0,0, 0,0, 0,0, 1, 2048, 1.f);

  // 8) g_scores (2-term A) -> planes (R1, vp dead); masked softmax in place
  gemm_g<64,2,1,1,0><<<dim3(16,1,128), blk, 0, stream>>>(
      gqs_hi, gqs_lo, kk_hi, gsc_hi, gsc_lo, mask_ws,
      64, 64,1024,2048, 65536L,4096L, 2097152L,64L, 2097152L,131072L, 16, 2048, scale);
  softmax_split<<<8192, blk, 0, stream>>>(gsc_hi, gsc_lo);

  // 9) gk/gv = g_attn @ {kk,vs} (dual MFMA einsum, KC=4; partials on dead W region)
  einsum_m<2><<<dim3(4,128), blk, 0, stream>>>(
      gsc_hi, gsc_lo, kk_hi, kk_lo, vs_hi, vs_lo, part1, part2,
      2048, 4, 2048, 1024, 2097152L, 131072L, 2097152L, 64L, 16, 128);
  reduce64<<<512, blk, 0, stream>>>(part1, gk_hi, gk_lo, 131072, 4);   // kk dead now
  reduce64<<<512, blk, 0, stream>>>(part2, gv_hi, gv_lo, 131072, 4);

  // 10) stage 2 (MFMA): l_attn (out1) + attn hi plane (over dead kk_lo)
  stage2_mfma<<<dim3(16,128), blk, 0, stream>>>(qs_hi, qs_lo, gk_hi, gk_lo,
      gv_hi, gv_lo, out1, attn_hi, scale);

  // 11) out0 = attn @ Wo (1-term, swizzled)
  gemm_g<128,1,0,0,1><<<dim3(8,128,1), blk, 0, stream>>>(
      attn_hi, nullptr, WoT_hi, out0, nullptr, nullptr,
      1024, 1024,1024,1024, 0,0, 0,0, 0,0, 1, 2048, 1.f);

  (void)in_sizes; (void)n_in; (void)out_size; (void)ws_size;
}